// Round 1
// 416.023 us; speedup vs baseline: 1.1843x; 1.1843x over previous
//
#include <hip/hip_runtime.h>
#include <hip/hip_bf16.h>
#include <math.h>

// B=4, S=2048, C=1024, H=16, HS=64
// Inputs (fp32, dict order): x[4,2048,1024], Wq/Wk/Wv[16,1024,64],
//                            Wp[1024,1024], bp[1024]
// Output: FP32 [4,2048,1024]
// R9: flash rewritten to swapped-QK^T 32x32 MFMA structure (m214 recipe):
//     in-register softmax (no Ps LDS round-trip, no ds_swizzle reduce chains),
//     cvt_pk + permlane32_swap P redistribution, XOR-swizzled K/V LDS (T2),
//     defer-max rescale (T13), setprio around MFMA (T5).
//     QKV/out GEMMs + pack unchanged from R8.

typedef __bf16 bf16_t;
typedef __bf16 bf16x8 __attribute__((ext_vector_type(8)));
typedef __bf16 bf16x2 __attribute__((ext_vector_type(2)));
typedef float f32x4 __attribute__((ext_vector_type(4)));
typedef float f32x16 __attribute__((ext_vector_type(16)));

#define S_LEN 2048
#define C_DIM 1024
#define NHEAD 16
#define HS_DIM 64
#define MROWS 8192   // B*S

__device__ __forceinline__ void cvt8(bf16_t* dst, const float* __restrict__ src) {
  const float4 a = *(const float4*)src;
  const float4 b = *(const float4*)(src + 4);
  bf16x8 v;
  v[0] = (bf16_t)a.x; v[1] = (bf16_t)a.y; v[2] = (bf16_t)a.z; v[3] = (bf16_t)a.w;
  v[4] = (bf16_t)b.x; v[5] = (bf16_t)b.y; v[6] = (bf16_t)b.z; v[7] = (bf16_t)b.w;
  *(bf16x8*)dst = v;
}

// pack two f32 -> one u32 of 2xbf16 (compiler fuses to v_cvt_pk_bf16_f32; m240)
__device__ __forceinline__ unsigned int pk2(float a, float b) {
  union { bf16x2 h; unsigned int u; } t;
  t.h[0] = (bf16_t)a;
  t.h[1] = (bf16_t)b;
  return t.u;
}

// ---------------------------------------------------------------------------
// Pack Wq,Wk,Wv (fp32 [16,1024,64]) -> bf16 WT[3072,1024]:
// WT[wsel*1024+h*64+d][c] = W[h][c][d].
// ---------------------------------------------------------------------------
__global__ __launch_bounds__(256) void pack_w_kernel(
    const float* __restrict__ Wq, const float* __restrict__ Wk,
    const float* __restrict__ Wv, bf16_t* __restrict__ WT) {
  __shared__ __align__(16) float tile[64][68];
  const int wsel = blockIdx.z;
  const int h = blockIdx.y;
  const int c0 = blockIdx.x * 64;
  const float* W = (wsel == 0 ? Wq : (wsel == 1 ? Wk : Wv)) + (size_t)h * (C_DIM * HS_DIM);
  const int tr = threadIdx.x >> 2;          // 0..63 (c-row within tile)
  const int tc = (threadIdx.x & 3) << 4;    // 0,16,32,48
  #pragma unroll
  for (int j = 0; j < 16; j += 4)
    *(float4*)&tile[tr][tc + j] = *(const float4*)(W + (size_t)(c0 + tr) * HS_DIM + tc + j);
  __syncthreads();
  const int d = threadIdx.x >> 2;           // 0..63
  const int cb = (threadIdx.x & 3) << 4;    // 0,16,32,48
  bf16_t* dst = WT + ((size_t)(wsel * 1024 + h * 64 + d)) * C_DIM + c0 + cb;
  #pragma unroll
  for (int i = 0; i < 16; ++i) dst[i] = (bf16_t)tile[cb + i][d];
}

// ---------------------------------------------------------------------------
// QKV projection: x[8192,1024](fp32) x WT[3072,1024](bf16)^T.
// 128x128x64 tiles, 4 waves in 2x2, 4x4 accs/wave. Scatter epilogue.
// ---------------------------------------------------------------------------
__global__ __launch_bounds__(256) void gemm_qkv128(
    const float* __restrict__ x, const bf16_t* __restrict__ WT,
    bf16_t* __restrict__ Q, bf16_t* __restrict__ K, bf16_t* __restrict__ VT) {
  __shared__ __align__(16) bf16_t As[128][72];
  __shared__ __align__(16) bf16_t Bs[128][72];
  const int m0 = blockIdx.x * 128;
  const int n0 = blockIdx.y * 128;
  const int tid = threadIdx.x;
  const int wave = tid >> 6, lane = tid & 63, quad = lane >> 4, lid = lane & 15;
  const int ww = wave >> 1, wc = wave & 1;
  const int ar = tid >> 1, ac = (tid & 1) << 5;

  f32x4 acc[4][4] = {};

  for (int k0 = 0; k0 < C_DIM; k0 += 64) {
    #pragma unroll
    for (int j = 0; j < 32; j += 8)
      cvt8(&As[ar][ac + j], x + (size_t)(m0 + ar) * C_DIM + k0 + ac + j);
    #pragma unroll
    for (int j = 0; j < 32; j += 8)
      *(uint4*)&Bs[ar][ac + j] = *(const uint4*)(WT + (size_t)(n0 + ar) * C_DIM + k0 + ac + j);
    __syncthreads();
    #pragma unroll
    for (int c = 0; c < 2; ++c) {
      bf16x8 af[4], bfr[4];
      #pragma unroll
      for (int mt = 0; mt < 4; ++mt)
        af[mt] = *(const bf16x8*)&As[ww * 64 + mt * 16 + lid][c * 32 + quad * 8];
      #pragma unroll
      for (int nt = 0; nt < 4; ++nt)
        bfr[nt] = *(const bf16x8*)&Bs[wc * 64 + nt * 16 + lid][c * 32 + quad * 8];
      #pragma unroll
      for (int mt = 0; mt < 4; ++mt)
        #pragma unroll
        for (int nt = 0; nt < 4; ++nt)
          acc[mt][nt] = __builtin_amdgcn_mfma_f32_16x16x32_bf16(af[mt], bfr[nt], acc[mt][nt], 0, 0, 0);
    }
    __syncthreads();
  }

  #pragma unroll
  for (int mt = 0; mt < 4; ++mt) {
    #pragma unroll
    for (int nt = 0; nt < 4; ++nt) {
      #pragma unroll
      for (int r = 0; r < 4; ++r) {
        const int row = m0 + ww * 64 + mt * 16 + quad * 4 + r;
        const int col = n0 + wc * 64 + nt * 16 + lid;
        const int wsel = col >> 10, h = (col >> 6) & 15, d = col & 63;
        const bf16_t bv = (bf16_t)acc[mt][nt][r];
        if (wsel == 0) {
          Q[(size_t)row * C_DIM + h * HS_DIM + d] = bv;
        } else if (wsel == 1) {
          K[(size_t)row * C_DIM + h * HS_DIM + d] = bv;
        } else {
          const int b = row >> 11, s = row & 2047;
          VT[((size_t)(b * NHEAD + h) * HS_DIM + d) * S_LEN + s] = bv;
        }
      }
    }
  }
}

// ---------------------------------------------------------------------------
// Flash attention (causal), swapped-QK^T 32x32 structure.
// grid (16 qblocks LPT, 64 bh); block = 4 waves; each wave owns 32 Q rows
// (block Q tile = 128). KV tiles of 64, double-buffered LDS with register
// prefetch, ONE barrier per iteration.
//
// QK^T computed as S^T = mfma_32x32x16(A=K, B=Q): each lane (pair l, l+32)
// holds the full 64-wide P row of q = qw + (lane&31) in registers ->
// softmax max/sum are in-register trees + one shfl_xor(.,32).
// P -> bf16 A-fragments via cvt-pk pairs + permlane32_swap (T12).
// K/V LDS rows are 128B -> XOR swizzle col ^= (row&7)<<3 elements (T2).
// Defer-max (T13, THR=8 in exp2 domain) makes the O-rescale (and its
// 16-bpermute alpha broadcast) rare.
// ---------------------------------------------------------------------------
#define PACK_GROUP(SV, BASE, FR)                                         \
  {                                                                      \
    unsigned int w0 = pk2(SV[BASE + 0], SV[BASE + 1]);                   \
    unsigned int w1 = pk2(SV[BASE + 2], SV[BASE + 3]);                   \
    unsigned int w2 = pk2(SV[BASE + 4], SV[BASE + 5]);                   \
    unsigned int w3 = pk2(SV[BASE + 6], SV[BASE + 7]);                   \
    auto sA = __builtin_amdgcn_permlane32_swap(w0, w2, false, false);    \
    auto sB = __builtin_amdgcn_permlane32_swap(w1, w3, false, false);    \
    FR.u[0] = sA[0]; FR.u[2] = sA[1];                                    \
    FR.u[1] = sB[0]; FR.u[3] = sB[1];                                    \
  }

union PFrag { bf16x8 v; unsigned int u[4]; };

__global__ __launch_bounds__(256, 2) void flash_attn_kernel(
    const bf16_t* __restrict__ Q,   // [8192,1024]
    const bf16_t* __restrict__ Kb,  // [8192,1024]
    const bf16_t* __restrict__ VT,  // [64,64,2048]
    bf16_t* __restrict__ O) {       // [8192,1024]
  __shared__ __align__(16) bf16_t Ks[2][64][64];
  __shared__ __align__(16) bf16_t Vs[2][64][64];
  const int s0 = (15 - blockIdx.x) * 128;    // LPT: long blocks first
  const int bh = blockIdx.y;
  const int b = bh >> 4, h = bh & 15;
  const int rb = b * S_LEN;
  const int tid = threadIdx.x;
  const int wave = tid >> 6, lane = tid & 63;
  const int l31 = lane & 31, hi = lane >> 5;
  const int qw = s0 + wave * 32;             // this wave's first q row
  const float cscale = 0.125f * 1.44269504f; // fold 1/sqrt(64) * log2(e)

  // staging coords: 256 thr x 16B covers 32 rows x 128B per pass (2 passes)
  const int srow = tid >> 3;                 // 0..31
  const int scol = (tid & 7) << 3;           // element col 0,8,...,56
  const int swcol = scol ^ ((srow & 7) << 3);// XOR-swizzled store col

  const bf16_t* kbase = Kb + (size_t)(rb + srow) * C_DIM + h * HS_DIM + scol;
  const bf16_t* vbase = VT + ((size_t)bh * HS_DIM + srow) * S_LEN + scol;

  // Q fragments (B-operand): col q = l31, chunk c: d = c*16 + hi*8 + j
  bf16x8 qfrag[4];
  {
    const bf16_t* qp = Q + (size_t)(rb + qw + l31) * C_DIM + h * HS_DIM + hi * 8;
    #pragma unroll
    for (int c = 0; c < 4; ++c) qfrag[c] = *(const bf16x8*)(qp + c * 16);
  }

  f32x16 oacc0 = {}, oacc1 = {};   // d-tiles 0 (d=l31) and 1 (d=32+l31)
  float m_i = -INFINITY, l_i = 0.f;

  const int nIter = (s0 >> 6) + 2;
  const int rsw = (lane & 7) << 3;           // read swizzle term (row&7 == lane&7)

  // Prolog: stage tile 0 -> buffer 0
  {
    uint4 k0 = *(const uint4*)(kbase);
    uint4 k1 = *(const uint4*)(kbase + 32 * C_DIM);
    uint4 v0 = *(const uint4*)(vbase);
    uint4 v1 = *(const uint4*)(vbase + 32 * S_LEN);
    *(uint4*)&Ks[0][srow][swcol]      = k0;
    *(uint4*)&Ks[0][srow + 32][swcol] = k1;
    *(uint4*)&Vs[0][srow][swcol]      = v0;
    *(uint4*)&Vs[0][srow + 32][swcol] = v1;
  }
  __syncthreads();

  for (int i = 0; i < nIter; ++i) {
    const int pb = i & 1;
    const int t0 = i << 6;

    // register prefetch of next tile (overlaps compute)
    uint4 k0r, k1r, v0r, v1r;
    const bool haveNext = (i + 1 < nIter);
    if (haveNext) {
      const bf16_t* kp = kbase + (size_t)(t0 + 64) * C_DIM;
      const bf16_t* vp = vbase + (t0 + 64);
      k0r = *(const uint4*)(kp);
      k1r = *(const uint4*)(kp + 32 * C_DIM);
      v0r = *(const uint4*)(vp);
      v1r = *(const uint4*)(vp + 32 * S_LEN);
    }

    if (t0 < qw + 32) {   // wave-uniform causal skip
      // ---- QK^T (swapped): sacc[t][q], t-tiles 0/1 ----
      f32x16 sa0 = {}, sa1 = {};
      __builtin_amdgcn_s_setprio(1);
      #pragma unroll
      for (int c = 0; c < 4; ++c) {
        const int col = (c * 16 + hi * 8) ^ rsw;
        bf16x8 kf0 = *(const bf16x8*)&Ks[pb][l31][col];
        bf16x8 kf1 = *(const bf16x8*)&Ks[pb][l31 + 32][col];
        sa0 = __builtin_amdgcn_mfma_f32_32x32x16_bf16(kf0, qfrag[c], sa0, 0, 0, 0);
        sa1 = __builtin_amdgcn_mfma_f32_32x32x16_bf16(kf1, qfrag[c], sa1, 0, 0, 0);
      }
      __builtin_amdgcn_s_setprio(0);

      // scale + causal mask (diag tiles only)
      const bool diag = (t0 + 63 > qw);
      const int qg = qw + l31;
      #pragma unroll
      for (int r = 0; r < 16; ++r) {
        const int tr = (r & 3) + 8 * (r >> 2) + 4 * hi;
        float v0 = sa0[r] * cscale;
        float v1 = sa1[r] * cscale;
        if (diag) {
          if (t0 + tr > qg)      v0 = -INFINITY;
          if (t0 + 32 + tr > qg) v1 = -INFINITY;
        }
        sa0[r] = v0; sa1[r] = v1;
      }

      // in-register row max + cross-half combine
      float pmax = -INFINITY;
      #pragma unroll
      for (int r = 0; r < 16; ++r) pmax = fmaxf(pmax, fmaxf(sa0[r], sa1[r]));
      pmax = fmaxf(pmax, __shfl_xor(pmax, 32));

      // defer-max rescale (T13): only rescale when max grew by > 8 (exp2 dom)
      if (!__all(pmax <= m_i + 8.f)) {
        const float mnew = fmaxf(m_i, pmax);
        const float alpha = exp2f(m_i - mnew);
        m_i = mnew;
        l_i *= alpha;
        #pragma unroll
        for (int r = 0; r < 16; ++r) {
          const float av = __shfl(alpha, (r & 3) + 8 * (r >> 2) + 4 * hi);
          oacc0[r] *= av;
          oacc1[r] *= av;
        }
      }

      // P = exp2(s - m), row sum
      float rsum = 0.f;
      #pragma unroll
      for (int r = 0; r < 16; ++r) {
        const float p0 = exp2f(sa0[r] - m_i);
        const float p1 = exp2f(sa1[r] - m_i);
        sa0[r] = p0; sa1[r] = p1;
        rsum += p0 + p1;
      }
      rsum += __shfl_xor(rsum, 32);
      l_i += rsum;

      // pack P -> 4 A-frags (ks = t/16) via cvt-pk + permlane32_swap (T12)
      PFrag pf[4];
      PACK_GROUP(sa0, 0, pf[0])
      PACK_GROUP(sa0, 8, pf[1])
      PACK_GROUP(sa1, 0, pf[2])
      PACK_GROUP(sa1, 8, pf[3])

      // ---- PV ----
      __builtin_amdgcn_s_setprio(1);
      #pragma unroll
      for (int ks = 0; ks < 4; ++ks) {
        const int col = (ks * 16 + hi * 8) ^ rsw;
        bf16x8 vf0 = *(const bf16x8*)&Vs[pb][l31][col];
        bf16x8 vf1 = *(const bf16x8*)&Vs[pb][l31 + 32][col];
        oacc0 = __builtin_amdgcn_mfma_f32_32x32x16_bf16(pf[ks].v, vf0, oacc0, 0, 0, 0);
        oacc1 = __builtin_amdgcn_mfma_f32_32x32x16_bf16(pf[ks].v, vf1, oacc1, 0, 0, 0);
      }
      __builtin_amdgcn_s_setprio(0);
    }

    // write prefetched tile into the idle buffer; single barrier/iter
    if (haveNext) {
      *(uint4*)&Ks[1 - pb][srow][swcol]      = k0r;
      *(uint4*)&Ks[1 - pb][srow + 32][swcol] = k1r;
      *(uint4*)&Vs[1 - pb][srow][swcol]      = v0r;
      *(uint4*)&Vs[1 - pb][srow + 32][swcol] = v1r;
      __syncthreads();
    }
  }

  // epilogue: O = oacc / l  (broadcast 1/l from lane q to row layout)
  const float linv = 1.f / l_i;
  #pragma unroll
  for (int r = 0; r < 16; ++r) {
    const int qrow = (r & 3) + 8 * (r >> 2) + 4 * hi;
    const float inv = __shfl(linv, qrow);
    const int row = rb + qw + qrow;
    O[(size_t)row * C_DIM + h * HS_DIM + l31]      = (bf16_t)(oacc0[r] * inv);
    O[(size_t)row * C_DIM + h * HS_DIM + 32 + l31] = (bf16_t)(oacc1[r] * inv);
  }
}

// ---------------------------------------------------------------------------
// Output projection: out = O @ Wp^T + bp (fp32 stores). 128x128x64 tiles.
// ---------------------------------------------------------------------------
__global__ __launch_bounds__(256) void gemm_out128(
    const bf16_t* __restrict__ A,    // [8192,1024] O
    const float* __restrict__ Wp,    // [1024,1024]
    const float* __restrict__ bias,  // [1024]
    float* __restrict__ out) {       // [8192,1024] fp32
  __shared__ __align__(16) bf16_t As[128][72];
  __shared__ __align__(16) bf16_t Bs[128][72];
  const int m0 = blockIdx.x * 128;
  const int n0 = blockIdx.y * 128;
  const int tid = threadIdx.x;
  const int wave = tid >> 6, lane = tid & 63, quad = lane >> 4, lid = lane & 15;
  const int ww = wave >> 1, wc = wave & 1;
  const int ar = tid >> 1, ac = (tid & 1) << 5;

  f32x4 acc[4][4] = {};

  for (int k0 = 0; k0 < C_DIM; k0 += 64) {
    #pragma unroll
    for (int j = 0; j < 32; j += 8)
      *(uint4*)&As[ar][ac + j] = *(const uint4*)(A + (size_t)(m0 + ar) * C_DIM + k0 + ac + j);
    #pragma unroll
    for (int j = 0; j < 32; j += 8)
      cvt8(&Bs[ar][ac + j], Wp + (size_t)(n0 + ar) * C_DIM + k0 + ac + j);
    __syncthreads();
    #pragma unroll
    for (int c = 0; c < 2; ++c) {
      bf16x8 af[4], bfr[4];
      #pragma unroll
      for (int mt = 0; mt < 4; ++mt)
        af[mt] = *(const bf16x8*)&As[ww * 64 + mt * 16 + lid][c * 32 + quad * 8];
      #pragma unroll
      for (int nt = 0; nt < 4; ++nt)
        bfr[nt] = *(const bf16x8*)&Bs[wc * 64 + nt * 16 + lid][c * 32 + quad * 8];
      #pragma unroll
      for (int mt = 0; mt < 4; ++mt)
        #pragma unroll
        for (int nt = 0; nt < 4; ++nt)
          acc[mt][nt] = __builtin_amdgcn_mfma_f32_16x16x32_bf16(af[mt], bfr[nt], acc[mt][nt], 0, 0, 0);
    }
    __syncthreads();
  }

  #pragma unroll
  for (int mt = 0; mt < 4; ++mt) {
    #pragma unroll
    for (int nt = 0; nt < 4; ++nt) {
      #pragma unroll
      for (int r = 0; r < 4; ++r) {
        const int row = m0 + ww * 64 + mt * 16 + quad * 4 + r;
        const int col = n0 + wc * 64 + nt * 16 + lid;
        out[(size_t)row * C_DIM + col] = acc[mt][nt][r] + bias[col];
      }
    }
  }
}

// ---------------------------------------------------------------------------
extern "C" void kernel_launch(void* const* d_in, const int* in_sizes, int n_in,
                              void* d_out, int out_size, void* d_ws, size_t ws_size,
                              hipStream_t stream) {
  const float *x, *Wq, *Wk, *Wv, *Wp, *bp;
  if (in_sizes[0] == MROWS * C_DIM) {            // dict order (confirmed)
    x  = (const float*)d_in[0];
    Wq = (const float*)d_in[1];
    Wk = (const float*)d_in[2];
    Wv = (const float*)d_in[3];
    Wp = (const float*)d_in[4];
    bp = (const float*)d_in[5];
  } else {                                        // key-sorted hedge
    Wk = (const float*)d_in[0];
    Wp = (const float*)d_in[1];
    Wq = (const float*)d_in[2];
    Wv = (const float*)d_in[3];
    bp = (const float*)d_in[4];
    x  = (const float*)d_in[5];
  }
  float* out = (float*)d_out;

  // ws = 64 MB: [Ob 16MB (WT aliases its first 6MB; dead before flash)]
  //             [Qb 16MB][Kb 16MB][VTb 16MB]
  const size_t NB = (size_t)MROWS * C_DIM;   // 8 M elements
  bf16_t* ws  = (bf16_t*)d_ws;
  bf16_t* Ob  = ws;            // [8192,1024]
  bf16_t* WT  = ws;            // [3072,1024] — aliases Ob, dead after QKV GEMM
  bf16_t* Qb  = ws + NB;       // [8192,1024]
  bf16_t* Kb  = Qb + NB;       // [8192,1024]
  bf16_t* VTb = Kb + NB;       // [64,64,2048]

  pack_w_kernel<<<dim3(16, 16, 3), 256, 0, stream>>>(Wq, Wk, Wv, WT);
  gemm_qkv128<<<dim3(64, 24), 256, 0, stream>>>(x, WT, Qb, Kb, VTb);
  flash_attn_kernel<<<dim3(16, 64), 256, 0, stream>>>(Qb, Kb, VTb, Ob);
  gemm_out128<<<dim3(64, 8), 256, 0, stream>>>(Ob, Wp, bp, out);
}

// Round 2
// 348.949 us; speedup vs baseline: 1.4119x; 1.1922x over previous
//
#include <hip/hip_runtime.h>
#include <hip/hip_bf16.h>
#include <math.h>

// B=4, S=2048, C=1024, H=16, HS=64
// Inputs (fp32, dict order): x[4,2048,1024], Wq/Wk/Wv[16,1024,64],
//                            Wp[1024,1024], bp[1024]
// Output: FP32 [4,2048,1024]
// R10: GEMMs rewritten to m97 structure (global_load_lds width=16 staging,
//      linear [128][64] LDS, 2-barrier K-loop). x pre-converted to bf16 into
//      d_out scratch; Wp converted to bf16 into Qb region post-flash.
//      V^T epilogue stores vectorized 2B->8B. Flash unchanged from R9.

typedef __bf16 bf16_t;
typedef __bf16 bf16x4_t __attribute__((ext_vector_type(4)));
typedef __bf16 bf16x8 __attribute__((ext_vector_type(8)));
typedef __bf16 bf16x2 __attribute__((ext_vector_type(2)));
typedef float f32x4 __attribute__((ext_vector_type(4)));
typedef float f32x16 __attribute__((ext_vector_type(16)));

#define S_LEN 2048
#define C_DIM 1024
#define NHEAD 16
#define HS_DIM 64
#define MROWS 8192   // B*S

__device__ __forceinline__ void cvt8(bf16_t* dst, const float* __restrict__ src) {
  const float4 a = *(const float4*)src;
  const float4 b = *(const float4*)(src + 4);
  bf16x8 v;
  v[0] = (bf16_t)a.x; v[1] = (bf16_t)a.y; v[2] = (bf16_t)a.z; v[3] = (bf16_t)a.w;
  v[4] = (bf16_t)b.x; v[5] = (bf16_t)b.y; v[6] = (bf16_t)b.z; v[7] = (bf16_t)b.w;
  *(bf16x8*)dst = v;
}

// pack two f32 -> one u32 of 2xbf16 (compiler fuses to v_cvt_pk_bf16_f32; m240)
__device__ __forceinline__ unsigned int pk2(float a, float b) {
  union { bf16x2 h; unsigned int u; } t;
  t.h[0] = (bf16_t)a;
  t.h[1] = (bf16_t)b;
  return t.u;
}

// async global->LDS, 16B per lane; LDS dest = wave-uniform base + lane*16
__device__ __forceinline__ void gload16(const bf16_t* g, bf16_t* l) {
  __builtin_amdgcn_global_load_lds(
      (const __attribute__((address_space(1))) unsigned int*)(const void*)g,
      (__attribute__((address_space(3))) unsigned int*)(void*)l,
      16, 0, 0);
}

// ---------------------------------------------------------------------------
// Elementwise fp32 -> bf16 convert (8 elems/thread). Used for x and Wp.
// ---------------------------------------------------------------------------
__global__ __launch_bounds__(256) void convert_bf16(
    const float* __restrict__ src, bf16_t* __restrict__ dst) {
  const size_t i = ((size_t)blockIdx.x * 256 + threadIdx.x) * 8;
  cvt8(dst + i, src + i);
}

// ---------------------------------------------------------------------------
// Pack Wq,Wk,Wv (fp32 [16,1024,64]) -> bf16 WT[3072,1024]:
// WT[wsel*1024+h*64+d][c] = W[h][c][d].
// ---------------------------------------------------------------------------
__global__ __launch_bounds__(256) void pack_w_kernel(
    const float* __restrict__ Wq, const float* __restrict__ Wk,
    const float* __restrict__ Wv, bf16_t* __restrict__ WT) {
  __shared__ __align__(16) float tile[64][68];
  const int wsel = blockIdx.z;
  const int h = blockIdx.y;
  const int c0 = blockIdx.x * 64;
  const float* W = (wsel == 0 ? Wq : (wsel == 1 ? Wk : Wv)) + (size_t)h * (C_DIM * HS_DIM);
  const int tr = threadIdx.x >> 2;          // 0..63 (c-row within tile)
  const int tc = (threadIdx.x & 3) << 4;    // 0,16,32,48
  #pragma unroll
  for (int j = 0; j < 16; j += 4)
    *(float4*)&tile[tr][tc + j] = *(const float4*)(W + (size_t)(c0 + tr) * HS_DIM + tc + j);
  __syncthreads();
  const int d = threadIdx.x >> 2;           // 0..63
  const int cb = (threadIdx.x & 3) << 4;    // 0,16,32,48
  bf16_t* dst = WT + ((size_t)(wsel * 1024 + h * 64 + d)) * C_DIM + c0 + cb;
  #pragma unroll
  for (int i = 0; i < 16; ++i) dst[i] = (bf16_t)tile[cb + i][d];
}

// ---------------------------------------------------------------------------
// QKV projection: xb[8192,1024](bf16) x WT[3072,1024](bf16)^T.
// m97 structure: 128x128x64 tiles, linear LDS [128][64], global_load_lds
// width=16 staging, 2 barriers per K-step. 4 waves 2x2, 4x4 accs/wave.
// Scatter epilogue (V^T stores vectorized 8B).
// ---------------------------------------------------------------------------
__global__ __launch_bounds__(256) void gemm_qkv128(
    const bf16_t* __restrict__ A, const bf16_t* __restrict__ WT,
    bf16_t* __restrict__ Q, bf16_t* __restrict__ K, bf16_t* __restrict__ VT) {
  __shared__ __align__(16) bf16_t As[128 * 64];
  __shared__ __align__(16) bf16_t Bs[128 * 64];
  const int m0 = blockIdx.x * 128;
  const int n0 = blockIdx.y * 128;
  const int tid = threadIdx.x;
  const int wave = tid >> 6, lane = tid & 63, quad = lane >> 4, lid = lane & 15;
  const int ww = wave >> 1, wc = wave & 1;
  const int lr = lane >> 3;                 // 0..7 (row within 8-row chunk)
  const int lc = (lane & 7) << 3;           // element col 0,8,...,56

  f32x4 acc[4][4] = {};

  for (int k0 = 0; k0 < C_DIM; k0 += 64) {
    #pragma unroll
    for (int j = 0; j < 4; ++j) {
      const int row = wave * 32 + j * 8;
      gload16(A  + (size_t)(m0 + row + lr) * C_DIM + k0 + lc, As + row * 64);
      gload16(WT + (size_t)(n0 + row + lr) * C_DIM + k0 + lc, Bs + row * 64);
    }
    __syncthreads();
    #pragma unroll
    for (int c = 0; c < 2; ++c) {
      bf16x8 af[4], bfr[4];
      #pragma unroll
      for (int mt = 0; mt < 4; ++mt)
        af[mt] = *(const bf16x8*)&As[(ww * 64 + mt * 16 + lid) * 64 + c * 32 + quad * 8];
      #pragma unroll
      for (int nt = 0; nt < 4; ++nt)
        bfr[nt] = *(const bf16x8*)&Bs[(wc * 64 + nt * 16 + lid) * 64 + c * 32 + quad * 8];
      #pragma unroll
      for (int mt = 0; mt < 4; ++mt)
        #pragma unroll
        for (int nt = 0; nt < 4; ++nt)
          acc[mt][nt] = __builtin_amdgcn_mfma_f32_16x16x32_bf16(af[mt], bfr[nt], acc[mt][nt], 0, 0, 0);
    }
    __syncthreads();
  }

  // wsel is block-uniform (each 128-col block lies inside one of Q/K/V)
  const int wsel = n0 >> 10;
  #pragma unroll
  for (int mt = 0; mt < 4; ++mt) {
    #pragma unroll
    for (int nt = 0; nt < 4; ++nt) {
      const int row0 = m0 + ww * 64 + mt * 16 + quad * 4;
      const int col = n0 + wc * 64 + nt * 16 + lid;
      const int h = (col >> 6) & 15, d = col & 63;
      if (wsel == 2) {
        // 4 consecutive s values -> one 8B store
        bf16x4_t pv;
        #pragma unroll
        for (int r = 0; r < 4; ++r) pv[r] = (bf16_t)acc[mt][nt][r];
        const int b = row0 >> 11, s = row0 & 2047;
        *(bf16x4_t*)&VT[((size_t)(b * NHEAD + h) * HS_DIM + d) * S_LEN + s] = pv;
      } else {
        bf16_t* dst = (wsel == 0 ? Q : K);
        #pragma unroll
        for (int r = 0; r < 4; ++r)
          dst[(size_t)(row0 + r) * C_DIM + h * HS_DIM + d] = (bf16_t)acc[mt][nt][r];
      }
    }
  }
}

// ---------------------------------------------------------------------------
// Flash attention (causal), swapped-QK^T 32x32 structure (R9, unchanged).
// ---------------------------------------------------------------------------
#define PACK_GROUP(SV, BASE, FR)                                         \
  {                                                                      \
    unsigned int w0 = pk2(SV[BASE + 0], SV[BASE + 1]);                   \
    unsigned int w1 = pk2(SV[BASE + 2], SV[BASE + 3]);                   \
    unsigned int w2 = pk2(SV[BASE + 4], SV[BASE + 5]);                   \
    unsigned int w3 = pk2(SV[BASE + 6], SV[BASE + 7]);                   \
    auto sA = __builtin_amdgcn_permlane32_swap(w0, w2, false, false);    \
    auto sB = __builtin_amdgcn_permlane32_swap(w1, w3, false, false);    \
    FR.u[0] = sA[0]; FR.u[2] = sA[1];                                    \
    FR.u[1] = sB[0]; FR.u[3] = sB[1];                                    \
  }

union PFrag { bf16x8 v; unsigned int u[4]; };

__global__ __launch_bounds__(256, 2) void flash_attn_kernel(
    const bf16_t* __restrict__ Q,   // [8192,1024]
    const bf16_t* __restrict__ Kb,  // [8192,1024]
    const bf16_t* __restrict__ VT,  // [64,64,2048]
    bf16_t* __restrict__ O) {       // [8192,1024]
  __shared__ __align__(16) bf16_t Ks[2][64][64];
  __shared__ __align__(16) bf16_t Vs[2][64][64];
  const int s0 = (15 - blockIdx.x) * 128;    // LPT: long blocks first
  const int bh = blockIdx.y;
  const int b = bh >> 4, h = bh & 15;
  const int rb = b * S_LEN;
  const int tid = threadIdx.x;
  const int wave = tid >> 6, lane = tid & 63;
  const int l31 = lane & 31, hi = lane >> 5;
  const int qw = s0 + wave * 32;             // this wave's first q row
  const float cscale = 0.125f * 1.44269504f; // fold 1/sqrt(64) * log2(e)

  // staging coords: 256 thr x 16B covers 32 rows x 128B per pass (2 passes)
  const int srow = tid >> 3;                 // 0..31
  const int scol = (tid & 7) << 3;           // element col 0,8,...,56
  const int swcol = scol ^ ((srow & 7) << 3);// XOR-swizzled store col

  const bf16_t* kbase = Kb + (size_t)(rb + srow) * C_DIM + h * HS_DIM + scol;
  const bf16_t* vbase = VT + ((size_t)bh * HS_DIM + srow) * S_LEN + scol;

  // Q fragments (B-operand): col q = l31, chunk c: d = c*16 + hi*8 + j
  bf16x8 qfrag[4];
  {
    const bf16_t* qp = Q + (size_t)(rb + qw + l31) * C_DIM + h * HS_DIM + hi * 8;
    #pragma unroll
    for (int c = 0; c < 4; ++c) qfrag[c] = *(const bf16x8*)(qp + c * 16);
  }

  f32x16 oacc0 = {}, oacc1 = {};   // d-tiles 0 (d=l31) and 1 (d=32+l31)
  float m_i = -INFINITY, l_i = 0.f;

  const int nIter = (s0 >> 6) + 2;
  const int rsw = (lane & 7) << 3;           // read swizzle term (row&7 == lane&7)

  // Prolog: stage tile 0 -> buffer 0
  {
    uint4 k0 = *(const uint4*)(kbase);
    uint4 k1 = *(const uint4*)(kbase + 32 * C_DIM);
    uint4 v0 = *(const uint4*)(vbase);
    uint4 v1 = *(const uint4*)(vbase + 32 * S_LEN);
    *(uint4*)&Ks[0][srow][swcol]      = k0;
    *(uint4*)&Ks[0][srow + 32][swcol] = k1;
    *(uint4*)&Vs[0][srow][swcol]      = v0;
    *(uint4*)&Vs[0][srow + 32][swcol] = v1;
  }
  __syncthreads();

  for (int i = 0; i < nIter; ++i) {
    const int pb = i & 1;
    const int t0 = i << 6;

    // register prefetch of next tile (overlaps compute)
    uint4 k0r, k1r, v0r, v1r;
    const bool haveNext = (i + 1 < nIter);
    if (haveNext) {
      const bf16_t* kp = kbase + (size_t)(t0 + 64) * C_DIM;
      const bf16_t* vp = vbase + (t0 + 64);
      k0r = *(const uint4*)(kp);
      k1r = *(const uint4*)(kp + 32 * C_DIM);
      v0r = *(const uint4*)(vp);
      v1r = *(const uint4*)(vp + 32 * S_LEN);
    }

    if (t0 < qw + 32) {   // wave-uniform causal skip
      // ---- QK^T (swapped): sacc[t][q], t-tiles 0/1 ----
      f32x16 sa0 = {}, sa1 = {};
      __builtin_amdgcn_s_setprio(1);
      #pragma unroll
      for (int c = 0; c < 4; ++c) {
        const int col = (c * 16 + hi * 8) ^ rsw;
        bf16x8 kf0 = *(const bf16x8*)&Ks[pb][l31][col];
        bf16x8 kf1 = *(const bf16x8*)&Ks[pb][l31 + 32][col];
        sa0 = __builtin_amdgcn_mfma_f32_32x32x16_bf16(kf0, qfrag[c], sa0, 0, 0, 0);
        sa1 = __builtin_amdgcn_mfma_f32_32x32x16_bf16(kf1, qfrag[c], sa1, 0, 0, 0);
      }
      __builtin_amdgcn_s_setprio(0);

      // scale + causal mask (diag tiles only)
      const bool diag = (t0 + 63 > qw);
      const int qg = qw + l31;
      #pragma unroll
      for (int r = 0; r < 16; ++r) {
        const int tr = (r & 3) + 8 * (r >> 2) + 4 * hi;
        float v0 = sa0[r] * cscale;
        float v1 = sa1[r] * cscale;
        if (diag) {
          if (t0 + tr > qg)      v0 = -INFINITY;
          if (t0 + 32 + tr > qg) v1 = -INFINITY;
        }
        sa0[r] = v0; sa1[r] = v1;
      }

      // in-register row max + cross-half combine
      float pmax = -INFINITY;
      #pragma unroll
      for (int r = 0; r < 16; ++r) pmax = fmaxf(pmax, fmaxf(sa0[r], sa1[r]));
      pmax = fmaxf(pmax, __shfl_xor(pmax, 32));

      // defer-max rescale (T13): only rescale when max grew by > 8 (exp2 dom)
      if (!__all(pmax <= m_i + 8.f)) {
        const float mnew = fmaxf(m_i, pmax);
        const float alpha = exp2f(m_i - mnew);
        m_i = mnew;
        l_i *= alpha;
        #pragma unroll
        for (int r = 0; r < 16; ++r) {
          const float av = __shfl(alpha, (r & 3) + 8 * (r >> 2) + 4 * hi);
          oacc0[r] *= av;
          oacc1[r] *= av;
        }
      }

      // P = exp2(s - m), row sum
      float rsum = 0.f;
      #pragma unroll
      for (int r = 0; r < 16; ++r) {
        const float p0 = exp2f(sa0[r] - m_i);
        const float p1 = exp2f(sa1[r] - m_i);
        sa0[r] = p0; sa1[r] = p1;
        rsum += p0 + p1;
      }
      rsum += __shfl_xor(rsum, 32);
      l_i += rsum;

      // pack P -> 4 A-frags (ks = t/16) via cvt-pk + permlane32_swap (T12)
      PFrag pf[4];
      PACK_GROUP(sa0, 0, pf[0])
      PACK_GROUP(sa0, 8, pf[1])
      PACK_GROUP(sa1, 0, pf[2])
      PACK_GROUP(sa1, 8, pf[3])

      // ---- PV ----
      __builtin_amdgcn_s_setprio(1);
      #pragma unroll
      for (int ks = 0; ks < 4; ++ks) {
        const int col = (ks * 16 + hi * 8) ^ rsw;
        bf16x8 vf0 = *(const bf16x8*)&Vs[pb][l31][col];
        bf16x8 vf1 = *(const bf16x8*)&Vs[pb][l31 + 32][col];
        oacc0 = __builtin_amdgcn_mfma_f32_32x32x16_bf16(pf[ks].v, vf0, oacc0, 0, 0, 0);
        oacc1 = __builtin_amdgcn_mfma_f32_32x32x16_bf16(pf[ks].v, vf1, oacc1, 0, 0, 0);
      }
      __builtin_amdgcn_s_setprio(0);
    }

    // write prefetched tile into the idle buffer; single barrier/iter
    if (haveNext) {
      *(uint4*)&Ks[1 - pb][srow][swcol]      = k0r;
      *(uint4*)&Ks[1 - pb][srow + 32][swcol] = k1r;
      *(uint4*)&Vs[1 - pb][srow][swcol]      = v0r;
      *(uint4*)&Vs[1 - pb][srow + 32][swcol] = v1r;
      __syncthreads();
    }
  }

  // epilogue: O = oacc / l  (broadcast 1/l from lane q to row layout)
  const float linv = 1.f / l_i;
  #pragma unroll
  for (int r = 0; r < 16; ++r) {
    const int qrow = (r & 3) + 8 * (r >> 2) + 4 * hi;
    const float inv = __shfl(linv, qrow);
    const int row = rb + qw + qrow;
    O[(size_t)row * C_DIM + h * HS_DIM + l31]      = (bf16_t)(oacc0[r] * inv);
    O[(size_t)row * C_DIM + h * HS_DIM + 32 + l31] = (bf16_t)(oacc1[r] * inv);
  }
}

// ---------------------------------------------------------------------------
// Output projection: out = O @ WpT^T + bp (fp32 stores). m97 structure,
// both operands bf16 via global_load_lds.
// ---------------------------------------------------------------------------
__global__ __launch_bounds__(256) void gemm_out128(
    const bf16_t* __restrict__ A,    // [8192,1024] O (bf16)
    const bf16_t* __restrict__ Bw,   // [1024,1024] Wp (bf16)
    const float* __restrict__ bias,  // [1024]
    float* __restrict__ out) {       // [8192,1024] fp32
  __shared__ __align__(16) bf16_t As[128 * 64];
  __shared__ __align__(16) bf16_t Bs[128 * 64];
  const int m0 = blockIdx.x * 128;
  const int n0 = blockIdx.y * 128;
  const int tid = threadIdx.x;
  const int wave = tid >> 6, lane = tid & 63, quad = lane >> 4, lid = lane & 15;
  const int ww = wave >> 1, wc = wave & 1;
  const int lr = lane >> 3;
  const int lc = (lane & 7) << 3;

  f32x4 acc[4][4] = {};

  for (int k0 = 0; k0 < C_DIM; k0 += 64) {
    #pragma unroll
    for (int j = 0; j < 4; ++j) {
      const int row = wave * 32 + j * 8;
      gload16(A  + (size_t)(m0 + row + lr) * C_DIM + k0 + lc, As + row * 64);
      gload16(Bw + (size_t)(n0 + row + lr) * C_DIM + k0 + lc, Bs + row * 64);
    }
    __syncthreads();
    #pragma unroll
    for (int c = 0; c < 2; ++c) {
      bf16x8 af[4], bfr[4];
      #pragma unroll
      for (int mt = 0; mt < 4; ++mt)
        af[mt] = *(const bf16x8*)&As[(ww * 64 + mt * 16 + lid) * 64 + c * 32 + quad * 8];
      #pragma unroll
      for (int nt = 0; nt < 4; ++nt)
        bfr[nt] = *(const bf16x8*)&Bs[(wc * 64 + nt * 16 + lid) * 64 + c * 32 + quad * 8];
      #pragma unroll
      for (int mt = 0; mt < 4; ++mt)
        #pragma unroll
        for (int nt = 0; nt < 4; ++nt)
          acc[mt][nt] = __builtin_amdgcn_mfma_f32_16x16x32_bf16(af[mt], bfr[nt], acc[mt][nt], 0, 0, 0);
    }
    __syncthreads();
  }

  #pragma unroll
  for (int mt = 0; mt < 4; ++mt) {
    #pragma unroll
    for (int nt = 0; nt < 4; ++nt) {
      #pragma unroll
      for (int r = 0; r < 4; ++r) {
        const int row = m0 + ww * 64 + mt * 16 + quad * 4 + r;
        const int col = n0 + wc * 64 + nt * 16 + lid;
        out[(size_t)row * C_DIM + col] = acc[mt][nt][r] + bias[col];
      }
    }
  }
}

// ---------------------------------------------------------------------------
extern "C" void kernel_launch(void* const* d_in, const int* in_sizes, int n_in,
                              void* d_out, int out_size, void* d_ws, size_t ws_size,
                              hipStream_t stream) {
  const float *x, *Wq, *Wk, *Wv, *Wp, *bp;
  if (in_sizes[0] == MROWS * C_DIM) {            // dict order (confirmed)
    x  = (const float*)d_in[0];
    Wq = (const float*)d_in[1];
    Wk = (const float*)d_in[2];
    Wv = (const float*)d_in[3];
    Wp = (const float*)d_in[4];
    bp = (const float*)d_in[5];
  } else {                                        // key-sorted hedge
    Wk = (const float*)d_in[0];
    Wp = (const float*)d_in[1];
    Wq = (const float*)d_in[2];
    Wv = (const float*)d_in[3];
    bp = (const float*)d_in[4];
    x  = (const float*)d_in[5];
  }
  float* out = (float*)d_out;

  // ws = 64 MB: [Ob 16MB (WT aliases its first 6MB; dead before flash;
  //              WpT aliases Qb after flash)] [Qb 16MB][Kb 16MB][VTb 16MB]
  // xb (bf16 x) lives in the first 16MB of d_out (dead before gemm_out writes).
  const size_t NB = (size_t)MROWS * C_DIM;   // 8 M elements
  bf16_t* ws  = (bf16_t*)d_ws;
  bf16_t* Ob  = ws;            // [8192,1024]
  bf16_t* WT  = ws;            // [3072,1024] — aliases Ob, dead after QKV GEMM
  bf16_t* Qb  = ws + NB;       // [8192,1024]
  bf16_t* Kb  = Qb + NB;       // [8192,1024]
  bf16_t* VTb = Kb + NB;       // [64,64,2048]
  bf16_t* WpT = Qb;            // [1024,1024] — aliases Qb, written after flash
  bf16_t* xb  = (bf16_t*)d_out;// [8192,1024] — scratch in output buffer

  pack_w_kernel<<<dim3(16, 16, 3), 256, 0, stream>>>(Wq, Wk, Wv, WT);
  convert_bf16<<<dim3(4096), 256, 0, stream>>>(x, xb);
  gemm_qkv128<<<dim3(64, 24), 256, 0, stream>>>(xb, WT, Qb, Kb, VTb);
  flash_attn_kernel<<<dim3(16, 64), 256, 0, stream>>>(Qb, Kb, VTb, Ob);
  convert_bf16<<<dim3(512), 256, 0, stream>>>(Wp, WpT);
  gemm_out128<<<dim3(64, 8), 256, 0, stream>>>(Ob, WpT, bp, out);
}

// Round 3
// 282.783 us; speedup vs baseline: 1.7423x; 1.2340x over previous
//
#include <hip/hip_runtime.h>
#include <hip/hip_bf16.h>
#include <math.h>

// B=4, S=2048, C=1024, H=16, HS=64
// Inputs (fp32, dict order): x[4,2048,1024], Wq/Wk/Wv[16,1024,64],
//                            Wp[1024,1024], bp[1024]
// Output: FP32 [4,2048,1024]
// R11: flash load-balance rewrite:
//  - diagonal pairing: each block does q-tiles x and 15-x (uniform 34 iters);
//    fixes the id%256 congruence that put equal-length blocks on one CU
//    (R10 counters: 15% occupancy while 15/16 of machine drained).
//  - flat grid 512, id%8 == bh%8 -> one bh's KV pinned to one XCD L2.
//  - Q pre-scaled by 0.125*log2e at QKV-GEMM epilogue; flash drops the
//    per-iter 32x v_mul and skips mask loop on non-diag tiles.
// GEMMs/pack/convert unchanged from R10.

typedef __bf16 bf16_t;
typedef __bf16 bf16x4_t __attribute__((ext_vector_type(4)));
typedef __bf16 bf16x8 __attribute__((ext_vector_type(8)));
typedef __bf16 bf16x2 __attribute__((ext_vector_type(2)));
typedef float f32x4 __attribute__((ext_vector_type(4)));
typedef float f32x16 __attribute__((ext_vector_type(16)));

#define S_LEN 2048
#define C_DIM 1024
#define NHEAD 16
#define HS_DIM 64
#define MROWS 8192   // B*S
#define QSCALE 0.18033688011112042f  // 0.125 * log2(e)

__device__ __forceinline__ void cvt8(bf16_t* dst, const float* __restrict__ src) {
  const float4 a = *(const float4*)src;
  const float4 b = *(const float4*)(src + 4);
  bf16x8 v;
  v[0] = (bf16_t)a.x; v[1] = (bf16_t)a.y; v[2] = (bf16_t)a.z; v[3] = (bf16_t)a.w;
  v[4] = (bf16_t)b.x; v[5] = (bf16_t)b.y; v[6] = (bf16_t)b.z; v[7] = (bf16_t)b.w;
  *(bf16x8*)dst = v;
}

// pack two f32 -> one u32 of 2xbf16 (compiler fuses to v_cvt_pk_bf16_f32; m240)
__device__ __forceinline__ unsigned int pk2(float a, float b) {
  union { bf16x2 h; unsigned int u; } t;
  t.h[0] = (bf16_t)a;
  t.h[1] = (bf16_t)b;
  return t.u;
}

// async global->LDS, 16B per lane; LDS dest = wave-uniform base + lane*16
__device__ __forceinline__ void gload16(const bf16_t* g, bf16_t* l) {
  __builtin_amdgcn_global_load_lds(
      (const __attribute__((address_space(1))) unsigned int*)(const void*)g,
      (__attribute__((address_space(3))) unsigned int*)(void*)l,
      16, 0, 0);
}

// ---------------------------------------------------------------------------
// Elementwise fp32 -> bf16 convert (8 elems/thread). Used for x and Wp.
// ---------------------------------------------------------------------------
__global__ __launch_bounds__(256) void convert_bf16(
    const float* __restrict__ src, bf16_t* __restrict__ dst) {
  const size_t i = ((size_t)blockIdx.x * 256 + threadIdx.x) * 8;
  cvt8(dst + i, src + i);
}

// ---------------------------------------------------------------------------
// Pack Wq,Wk,Wv (fp32 [16,1024,64]) -> bf16 WT[3072,1024]:
// WT[wsel*1024+h*64+d][c] = W[h][c][d].
// ---------------------------------------------------------------------------
__global__ __launch_bounds__(256) void pack_w_kernel(
    const float* __restrict__ Wq, const float* __restrict__ Wk,
    const float* __restrict__ Wv, bf16_t* __restrict__ WT) {
  __shared__ __align__(16) float tile[64][68];
  const int wsel = blockIdx.z;
  const int h = blockIdx.y;
  const int c0 = blockIdx.x * 64;
  const float* W = (wsel == 0 ? Wq : (wsel == 1 ? Wk : Wv)) + (size_t)h * (C_DIM * HS_DIM);
  const int tr = threadIdx.x >> 2;          // 0..63 (c-row within tile)
  const int tc = (threadIdx.x & 3) << 4;    // 0,16,32,48
  #pragma unroll
  for (int j = 0; j < 16; j += 4)
    *(float4*)&tile[tr][tc + j] = *(const float4*)(W + (size_t)(c0 + tr) * HS_DIM + tc + j);
  __syncthreads();
  const int d = threadIdx.x >> 2;           // 0..63
  const int cb = (threadIdx.x & 3) << 4;    // 0,16,32,48
  bf16_t* dst = WT + ((size_t)(wsel * 1024 + h * 64 + d)) * C_DIM + c0 + cb;
  #pragma unroll
  for (int i = 0; i < 16; ++i) dst[i] = (bf16_t)tile[cb + i][d];
}

// ---------------------------------------------------------------------------
// QKV projection: xb[8192,1024](bf16) x WT[3072,1024](bf16)^T.
// m97 structure. Q epilogue pre-scales by QSCALE (folded softmax scale).
// ---------------------------------------------------------------------------
__global__ __launch_bounds__(256) void gemm_qkv128(
    const bf16_t* __restrict__ A, const bf16_t* __restrict__ WT,
    bf16_t* __restrict__ Q, bf16_t* __restrict__ K, bf16_t* __restrict__ VT) {
  __shared__ __align__(16) bf16_t As[128 * 64];
  __shared__ __align__(16) bf16_t Bs[128 * 64];
  const int m0 = blockIdx.x * 128;
  const int n0 = blockIdx.y * 128;
  const int tid = threadIdx.x;
  const int wave = tid >> 6, lane = tid & 63, quad = lane >> 4, lid = lane & 15;
  const int ww = wave >> 1, wc = wave & 1;
  const int lr = lane >> 3;                 // 0..7 (row within 8-row chunk)
  const int lc = (lane & 7) << 3;           // element col 0,8,...,56

  f32x4 acc[4][4] = {};

  for (int k0 = 0; k0 < C_DIM; k0 += 64) {
    #pragma unroll
    for (int j = 0; j < 4; ++j) {
      const int row = wave * 32 + j * 8;
      gload16(A  + (size_t)(m0 + row + lr) * C_DIM + k0 + lc, As + row * 64);
      gload16(WT + (size_t)(n0 + row + lr) * C_DIM + k0 + lc, Bs + row * 64);
    }
    __syncthreads();
    #pragma unroll
    for (int c = 0; c < 2; ++c) {
      bf16x8 af[4], bfr[4];
      #pragma unroll
      for (int mt = 0; mt < 4; ++mt)
        af[mt] = *(const bf16x8*)&As[(ww * 64 + mt * 16 + lid) * 64 + c * 32 + quad * 8];
      #pragma unroll
      for (int nt = 0; nt < 4; ++nt)
        bfr[nt] = *(const bf16x8*)&Bs[(wc * 64 + nt * 16 + lid) * 64 + c * 32 + quad * 8];
      #pragma unroll
      for (int mt = 0; mt < 4; ++mt)
        #pragma unroll
        for (int nt = 0; nt < 4; ++nt)
          acc[mt][nt] = __builtin_amdgcn_mfma_f32_16x16x32_bf16(af[mt], bfr[nt], acc[mt][nt], 0, 0, 0);
    }
    __syncthreads();
  }

  // wsel is block-uniform (each 128-col block lies inside one of Q/K/V)
  const int wsel = n0 >> 10;
  const float qs = (wsel == 0) ? QSCALE : 1.0f;
  #pragma unroll
  for (int mt = 0; mt < 4; ++mt) {
    #pragma unroll
    for (int nt = 0; nt < 4; ++nt) {
      const int row0 = m0 + ww * 64 + mt * 16 + quad * 4;
      const int col = n0 + wc * 64 + nt * 16 + lid;
      const int h = (col >> 6) & 15, d = col & 63;
      if (wsel == 2) {
        // 4 consecutive s values -> one 8B store
        bf16x4_t pv;
        #pragma unroll
        for (int r = 0; r < 4; ++r) pv[r] = (bf16_t)acc[mt][nt][r];
        const int b = row0 >> 11, s = row0 & 2047;
        *(bf16x4_t*)&VT[((size_t)(b * NHEAD + h) * HS_DIM + d) * S_LEN + s] = pv;
      } else {
        bf16_t* dst = (wsel == 0 ? Q : K);
        #pragma unroll
        for (int r = 0; r < 4; ++r)
          dst[(size_t)(row0 + r) * C_DIM + h * HS_DIM + d] = (bf16_t)(acc[mt][nt][r] * qs);
      }
    }
  }
}

// ---------------------------------------------------------------------------
// Flash attention (causal), swapped-QK^T 32x32 structure, diagonal-paired.
// grid flat 512: bh = id & 63 (-> id%8 == bh%8, bh's KV pinned to one XCD L2),
// bx = id >> 6 in 0..7. Each block runs q-tile (15-bx) then q-tile bx:
// 34 iterations total for EVERY block (uniform CU load).
// ---------------------------------------------------------------------------
#define PACK_GROUP(SV, BASE, FR)                                         \
  {                                                                      \
    unsigned int w0 = pk2(SV[BASE + 0], SV[BASE + 1]);                   \
    unsigned int w1 = pk2(SV[BASE + 2], SV[BASE + 3]);                   \
    unsigned int w2 = pk2(SV[BASE + 4], SV[BASE + 5]);                   \
    unsigned int w3 = pk2(SV[BASE + 6], SV[BASE + 7]);                   \
    auto sA = __builtin_amdgcn_permlane32_swap(w0, w2, false, false);    \
    auto sB = __builtin_amdgcn_permlane32_swap(w1, w3, false, false);    \
    FR.u[0] = sA[0]; FR.u[2] = sA[1];                                    \
    FR.u[1] = sB[0]; FR.u[3] = sB[1];                                    \
  }

union PFrag { bf16x8 v; unsigned int u[4]; };

__global__ __launch_bounds__(256, 2) void flash_attn_kernel(
    const bf16_t* __restrict__ Q,   // [8192,1024] (pre-scaled by QSCALE)
    const bf16_t* __restrict__ Kb,  // [8192,1024]
    const bf16_t* __restrict__ VT,  // [64,64,2048]
    bf16_t* __restrict__ O) {       // [8192,1024]
  __shared__ __align__(16) bf16_t Ks[2][64][64];
  __shared__ __align__(16) bf16_t Vs[2][64][64];
  const int id = blockIdx.x;
  const int bh = id & 63;                    // id%8 == bh%8 -> XCD locality
  const int bx = id >> 6;                    // 0..7
  const int b = bh >> 4, h = bh & 15;
  const int rb = b * S_LEN;
  const int tid = threadIdx.x;
  const int wave = tid >> 6, lane = tid & 63;
  const int l31 = lane & 31, hi = lane >> 5;

  // staging coords: 256 thr x 16B covers 32 rows x 128B per pass (2 passes)
  const int srow = tid >> 3;                 // 0..31
  const int scol = (tid & 7) << 3;           // element col 0,8,...,56
  const int swcol = scol ^ ((srow & 7) << 3);// XOR-swizzled store col
  const int rsw = (lane & 7) << 3;           // read swizzle term

  const bf16_t* kbase = Kb + (size_t)(rb + srow) * C_DIM + h * HS_DIM + scol;
  const bf16_t* vbase = VT + ((size_t)bh * HS_DIM + srow) * S_LEN + scol;

  #pragma unroll 1
  for (int phase = 0; phase < 2; ++phase) {
    const int s0 = (phase == 0 ? (15 - bx) : bx) * 128;
    const int qw = s0 + wave * 32;           // this wave's first q row

    // Q fragments (B-operand): col q = l31, chunk c: d = c*16 + hi*8 + j
    bf16x8 qfrag[4];
    {
      const bf16_t* qp = Q + (size_t)(rb + qw + l31) * C_DIM + h * HS_DIM + hi * 8;
      #pragma unroll
      for (int c = 0; c < 4; ++c) qfrag[c] = *(const bf16x8*)(qp + c * 16);
    }

    f32x16 oacc0 = {}, oacc1 = {};   // d-tiles 0 (d=l31) and 1 (d=32+l31)
    float m_i = -INFINITY, l_i = 0.f;
    const int nIter = (s0 >> 6) + 2;

    // Prolog: stage tile 0 -> buffer 0
    {
      uint4 k0 = *(const uint4*)(kbase);
      uint4 k1 = *(const uint4*)(kbase + 32 * C_DIM);
      uint4 v0 = *(const uint4*)(vbase);
      uint4 v1 = *(const uint4*)(vbase + 32 * S_LEN);
      *(uint4*)&Ks[0][srow][swcol]      = k0;
      *(uint4*)&Ks[0][srow + 32][swcol] = k1;
      *(uint4*)&Vs[0][srow][swcol]      = v0;
      *(uint4*)&Vs[0][srow + 32][swcol] = v1;
    }
    __syncthreads();

    for (int i = 0; i < nIter; ++i) {
      const int pb = i & 1;
      const int t0 = i << 6;

      // register prefetch of next tile (overlaps compute)
      uint4 k0r, k1r, v0r, v1r;
      const bool haveNext = (i + 1 < nIter);
      if (haveNext) {
        const bf16_t* kp = kbase + (size_t)(t0 + 64) * C_DIM;
        const bf16_t* vp = vbase + (t0 + 64);
        k0r = *(const uint4*)(kp);
        k1r = *(const uint4*)(kp + 32 * C_DIM);
        v0r = *(const uint4*)(vp);
        v1r = *(const uint4*)(vp + 32 * S_LEN);
      }

      if (t0 < qw + 32) {   // wave-uniform causal skip
        // ---- QK^T (swapped): sacc[t][q], t-tiles 0/1 ----
        f32x16 sa0 = {}, sa1 = {};
        __builtin_amdgcn_s_setprio(1);
        #pragma unroll
        for (int c = 0; c < 4; ++c) {
          const int col = (c * 16 + hi * 8) ^ rsw;
          bf16x8 kf0 = *(const bf16x8*)&Ks[pb][l31][col];
          bf16x8 kf1 = *(const bf16x8*)&Ks[pb][l31 + 32][col];
          sa0 = __builtin_amdgcn_mfma_f32_32x32x16_bf16(kf0, qfrag[c], sa0, 0, 0, 0);
          sa1 = __builtin_amdgcn_mfma_f32_32x32x16_bf16(kf1, qfrag[c], sa1, 0, 0, 0);
        }
        __builtin_amdgcn_s_setprio(0);

        // causal mask (diag tiles only; scores pre-scaled via Q)
        const bool diag = (t0 + 63 > qw);
        if (diag) {
          const int qg = qw + l31;
          #pragma unroll
          for (int r = 0; r < 16; ++r) {
            const int tr = (r & 3) + 8 * (r >> 2) + 4 * hi;
            if (t0 + tr > qg)      sa0[r] = -INFINITY;
            if (t0 + 32 + tr > qg) sa1[r] = -INFINITY;
          }
        }

        // in-register row max + cross-half combine
        float pmax = -INFINITY;
        #pragma unroll
        for (int r = 0; r < 16; ++r) pmax = fmaxf(pmax, fmaxf(sa0[r], sa1[r]));
        pmax = fmaxf(pmax, __shfl_xor(pmax, 32));

        // defer-max rescale (T13): only rescale when max grew by > 8 (exp2 dom)
        if (!__all(pmax <= m_i + 8.f)) {
          const float mnew = fmaxf(m_i, pmax);
          const float alpha = exp2f(m_i - mnew);
          m_i = mnew;
          l_i *= alpha;
          #pragma unroll
          for (int r = 0; r < 16; ++r) {
            const float av = __shfl(alpha, (r & 3) + 8 * (r >> 2) + 4 * hi);
            oacc0[r] *= av;
            oacc1[r] *= av;
          }
        }

        // P = exp2(s - m), row sum
        float rsum = 0.f;
        #pragma unroll
        for (int r = 0; r < 16; ++r) {
          const float p0 = exp2f(sa0[r] - m_i);
          const float p1 = exp2f(sa1[r] - m_i);
          sa0[r] = p0; sa1[r] = p1;
          rsum += p0 + p1;
        }
        rsum += __shfl_xor(rsum, 32);
        l_i += rsum;

        // pack P -> 4 A-frags (ks = t/16) via cvt-pk + permlane32_swap (T12)
        PFrag pf[4];
        PACK_GROUP(sa0, 0, pf[0])
        PACK_GROUP(sa0, 8, pf[1])
        PACK_GROUP(sa1, 0, pf[2])
        PACK_GROUP(sa1, 8, pf[3])

        // ---- PV ----
        __builtin_amdgcn_s_setprio(1);
        #pragma unroll
        for (int ks = 0; ks < 4; ++ks) {
          const int col = (ks * 16 + hi * 8) ^ rsw;
          bf16x8 vf0 = *(const bf16x8*)&Vs[pb][l31][col];
          bf16x8 vf1 = *(const bf16x8*)&Vs[pb][l31 + 32][col];
          oacc0 = __builtin_amdgcn_mfma_f32_32x32x16_bf16(pf[ks].v, vf0, oacc0, 0, 0, 0);
          oacc1 = __builtin_amdgcn_mfma_f32_32x32x16_bf16(pf[ks].v, vf1, oacc1, 0, 0, 0);
        }
        __builtin_amdgcn_s_setprio(0);
      }

      // write prefetched tile into the idle buffer; single barrier/iter
      if (haveNext) {
        *(uint4*)&Ks[1 - pb][srow][swcol]      = k0r;
        *(uint4*)&Ks[1 - pb][srow + 32][swcol] = k1r;
        *(uint4*)&Vs[1 - pb][srow][swcol]      = v0r;
        *(uint4*)&Vs[1 - pb][srow + 32][swcol] = v1r;
        __syncthreads();
      }
    }

    // epilogue: O = oacc / l  (broadcast 1/l from lane q to row layout)
    const float linv = 1.f / l_i;
    #pragma unroll
    for (int r = 0; r < 16; ++r) {
      const int qrow = (r & 3) + 8 * (r >> 2) + 4 * hi;
      const float inv = __shfl(linv, qrow);
      const int row = rb + qw + qrow;
      O[(size_t)row * C_DIM + h * HS_DIM + l31]      = (bf16_t)(oacc0[r] * inv);
      O[(size_t)row * C_DIM + h * HS_DIM + 32 + l31] = (bf16_t)(oacc1[r] * inv);
    }

    __syncthreads();   // LDS handoff to next phase's prolog
  }
}

// ---------------------------------------------------------------------------
// Output projection: out = O @ WpT^T + bp (fp32 stores). m97 structure,
// both operands bf16 via global_load_lds.
// ---------------------------------------------------------------------------
__global__ __launch_bounds__(256) void gemm_out128(
    const bf16_t* __restrict__ A,    // [8192,1024] O (bf16)
    const bf16_t* __restrict__ Bw,   // [1024,1024] Wp (bf16)
    const float* __restrict__ bias,  // [1024]
    float* __restrict__ out) {       // [8192,1024] fp32
  __shared__ __align__(16) bf16_t As[128 * 64];
  __shared__ __align__(16) bf16_t Bs[128 * 64];
  const int m0 = blockIdx.x * 128;
  const int n0 = blockIdx.y * 128;
  const int tid = threadIdx.x;
  const int wave = tid >> 6, lane = tid & 63, quad = lane >> 4, lid = lane & 15;
  const int ww = wave >> 1, wc = wave & 1;
  const int lr = lane >> 3;
  const int lc = (lane & 7) << 3;

  f32x4 acc[4][4] = {};

  for (int k0 = 0; k0 < C_DIM; k0 += 64) {
    #pragma unroll
    for (int j = 0; j < 4; ++j) {
      const int row = wave * 32 + j * 8;
      gload16(A  + (size_t)(m0 + row + lr) * C_DIM + k0 + lc, As + row * 64);
      gload16(Bw + (size_t)(n0 + row + lr) * C_DIM + k0 + lc, Bs + row * 64);
    }
    __syncthreads();
    #pragma unroll
    for (int c = 0; c < 2; ++c) {
      bf16x8 af[4], bfr[4];
      #pragma unroll
      for (int mt = 0; mt < 4; ++mt)
        af[mt] = *(const bf16x8*)&As[(ww * 64 + mt * 16 + lid) * 64 + c * 32 + quad * 8];
      #pragma unroll
      for (int nt = 0; nt < 4; ++nt)
        bfr[nt] = *(const bf16x8*)&Bs[(wc * 64 + nt * 16 + lid) * 64 + c * 32 + quad * 8];
      #pragma unroll
      for (int mt = 0; mt < 4; ++mt)
        #pragma unroll
        for (int nt = 0; nt < 4; ++nt)
          acc[mt][nt] = __builtin_amdgcn_mfma_f32_16x16x32_bf16(af[mt], bfr[nt], acc[mt][nt], 0, 0, 0);
    }
    __syncthreads();
  }

  #pragma unroll
  for (int mt = 0; mt < 4; ++mt) {
    #pragma unroll
    for (int nt = 0; nt < 4; ++nt) {
      #pragma unroll
      for (int r = 0; r < 4; ++r) {
        const int row = m0 + ww * 64 + mt * 16 + quad * 4 + r;
        const int col = n0 + wc * 64 + nt * 16 + lid;
        out[(size_t)row * C_DIM + col] = acc[mt][nt][r] + bias[col];
      }
    }
  }
}

// ---------------------------------------------------------------------------
extern "C" void kernel_launch(void* const* d_in, const int* in_sizes, int n_in,
                              void* d_out, int out_size, void* d_ws, size_t ws_size,
                              hipStream_t stream) {
  const float *x, *Wq, *Wk, *Wv, *Wp, *bp;
  if (in_sizes[0] == MROWS * C_DIM) {            // dict order (confirmed)
    x  = (const float*)d_in[0];
    Wq = (const float*)d_in[1];
    Wk = (const float*)d_in[2];
    Wv = (const float*)d_in[3];
    Wp = (const float*)d_in[4];
    bp = (const float*)d_in[5];
  } else {                                        // key-sorted hedge
    Wk = (const float*)d_in[0];
    Wp = (const float*)d_in[1];
    Wq = (const float*)d_in[2];
    Wv = (const float*)d_in[3];
    bp = (const float*)d_in[4];
    x  = (const float*)d_in[5];
  }
  float* out = (float*)d_out;

  // ws = 64 MB: [Ob 16MB (WT aliases its first 6MB; dead before flash;
  //              WpT aliases Qb after flash)] [Qb 16MB][Kb 16MB][VTb 16MB]
  // xb (bf16 x) lives in the first 16MB of d_out (dead before gemm_out writes).
  const size_t NB = (size_t)MROWS * C_DIM;   // 8 M elements
  bf16_t* ws  = (bf16_t*)d_ws;
  bf16_t* Ob  = ws;            // [8192,1024]
  bf16_t* WT  = ws;            // [3072,1024] — aliases Ob, dead after QKV GEMM
  bf16_t* Qb  = ws + NB;       // [8192,1024]
  bf16_t* Kb  = Qb + NB;       // [8192,1024]
  bf16_t* VTb = Kb + NB;       // [64,64,2048]
  bf16_t* WpT = Qb;            // [1024,1024] — aliases Qb, written after flash
  bf16_t* xb  = (bf16_t*)d_out;// [8192,1024] — scratch in output buffer

  pack_w_kernel<<<dim3(16, 16, 3), 256, 0, stream>>>(Wq, Wk, Wv, WT);
  convert_bf16<<<dim3(4096), 256, 0, stream>>>(x, xb);
  gemm_qkv128<<<dim3(64, 24), 256, 0, stream>>>(xb, WT, Qb, Kb, VTb);
  flash_attn_kernel<<<dim3(512), 256, 0, stream>>>(Qb, Kb, VTb, Ob);
  convert_bf16<<<dim3(512), 256, 0, stream>>>(Wp, WpT);
  gemm_out128<<<dim3(64, 8), 256, 0, stream>>>(Ob, WpT, bp, out);
}

// Round 4
// 277.427 us; speedup vs baseline: 1.7759x; 1.0193x over previous
//
#include <hip/hip_runtime.h>
#include <hip/hip_bf16.h>
#include <math.h>

// B=4, S=2048, C=1024, H=16, HS=64
// Inputs (fp32, dict order): x[4,2048,1024], Wq/Wk/Wv[16,1024,64],
//                            Wp[1024,1024], bp[1024]
// Output: FP32 [4,2048,1024]
// R12: both GEMMs -> counted-vmcnt double-buffered pipeline (T4):
//      raw s_barrier (no __syncthreads vmcnt(0) drain), vmcnt(8) steady-state,
//      stage issued AFTER the read-completion barrier (WAR-safe by program
//      order). LDS 2x32KB -> still 2 blocks/CU. T2/T5 omitted (null at 2ph).
//      Flash/pack/convert unchanged from R11.

typedef __bf16 bf16_t;
typedef __bf16 bf16x4_t __attribute__((ext_vector_type(4)));
typedef __bf16 bf16x8 __attribute__((ext_vector_type(8)));
typedef __bf16 bf16x2 __attribute__((ext_vector_type(2)));
typedef float f32x4 __attribute__((ext_vector_type(4)));
typedef float f32x16 __attribute__((ext_vector_type(16)));

#define S_LEN 2048
#define C_DIM 1024
#define NHEAD 16
#define HS_DIM 64
#define MROWS 8192   // B*S
#define QSCALE 0.18033688011112042f  // 0.125 * log2(e)

__device__ __forceinline__ void cvt8(bf16_t* dst, const float* __restrict__ src) {
  const float4 a = *(const float4*)src;
  const float4 b = *(const float4*)(src + 4);
  bf16x8 v;
  v[0] = (bf16_t)a.x; v[1] = (bf16_t)a.y; v[2] = (bf16_t)a.z; v[3] = (bf16_t)a.w;
  v[4] = (bf16_t)b.x; v[5] = (bf16_t)b.y; v[6] = (bf16_t)b.z; v[7] = (bf16_t)b.w;
  *(bf16x8*)dst = v;
}

// pack two f32 -> one u32 of 2xbf16 (compiler fuses to v_cvt_pk_bf16_f32; m240)
__device__ __forceinline__ unsigned int pk2(float a, float b) {
  union { bf16x2 h; unsigned int u; } t;
  t.h[0] = (bf16_t)a;
  t.h[1] = (bf16_t)b;
  return t.u;
}

// async global->LDS, 16B per lane; LDS dest = wave-uniform base + lane*16
__device__ __forceinline__ void gload16(const bf16_t* g, bf16_t* l) {
  __builtin_amdgcn_global_load_lds(
      (const __attribute__((address_space(1))) unsigned int*)(const void*)g,
      (__attribute__((address_space(3))) unsigned int*)(void*)l,
      16, 0, 0);
}

#define SBAR()  { __builtin_amdgcn_sched_barrier(0); \
                  __builtin_amdgcn_s_barrier();      \
                  __builtin_amdgcn_sched_barrier(0); }
#define VMCNT(N) { asm volatile("s_waitcnt vmcnt(" #N ")" ::: "memory"); \
                   __builtin_amdgcn_sched_barrier(0); }

// ---------------------------------------------------------------------------
// Elementwise fp32 -> bf16 convert (8 elems/thread). Used for x and Wp.
// ---------------------------------------------------------------------------
__global__ __launch_bounds__(256) void convert_bf16(
    const float* __restrict__ src, bf16_t* __restrict__ dst) {
  const size_t i = ((size_t)blockIdx.x * 256 + threadIdx.x) * 8;
  cvt8(dst + i, src + i);
}

// ---------------------------------------------------------------------------
// Pack Wq,Wk,Wv (fp32 [16,1024,64]) -> bf16 WT[3072,1024]:
// WT[wsel*1024+h*64+d][c] = W[h][c][d].
// ---------------------------------------------------------------------------
__global__ __launch_bounds__(256) void pack_w_kernel(
    const float* __restrict__ Wq, const float* __restrict__ Wk,
    const float* __restrict__ Wv, bf16_t* __restrict__ WT) {
  __shared__ __align__(16) float tile[64][68];
  const int wsel = blockIdx.z;
  const int h = blockIdx.y;
  const int c0 = blockIdx.x * 64;
  const float* W = (wsel == 0 ? Wq : (wsel == 1 ? Wk : Wv)) + (size_t)h * (C_DIM * HS_DIM);
  const int tr = threadIdx.x >> 2;          // 0..63 (c-row within tile)
  const int tc = (threadIdx.x & 3) << 4;    // 0,16,32,48
  #pragma unroll
  for (int j = 0; j < 16; j += 4)
    *(float4*)&tile[tr][tc + j] = *(const float4*)(W + (size_t)(c0 + tr) * HS_DIM + tc + j);
  __syncthreads();
  const int d = threadIdx.x >> 2;           // 0..63
  const int cb = (threadIdx.x & 3) << 4;    // 0,16,32,48
  bf16_t* dst = WT + ((size_t)(wsel * 1024 + h * 64 + d)) * C_DIM + c0 + cb;
  #pragma unroll
  for (int i = 0; i < 16; ++i) dst[i] = (bf16_t)tile[cb + i][d];
}

// ---------------------------------------------------------------------------
// QKV projection: xb[8192,1024](bf16) x WT[3072,1024](bf16)^T.
// Counted-vmcnt double-buffered pipeline (R12). 128x128x64 tiles, 4 waves 2x2,
// 4x4 accs/wave. Q epilogue pre-scales by QSCALE. V^T stores 8B.
// ---------------------------------------------------------------------------
__global__ __launch_bounds__(256) void gemm_qkv128(
    const bf16_t* __restrict__ A, const bf16_t* __restrict__ WT,
    bf16_t* __restrict__ Q, bf16_t* __restrict__ K, bf16_t* __restrict__ VT) {
  __shared__ __align__(16) bf16_t As[2][128 * 64];
  __shared__ __align__(16) bf16_t Bs[2][128 * 64];
  const int m0 = blockIdx.x * 128;
  const int n0 = blockIdx.y * 128;
  const int tid = threadIdx.x;
  const int wave = tid >> 6, lane = tid & 63, quad = lane >> 4, lid = lane & 15;
  const int ww = wave >> 1, wc = wave & 1;
  const int lr = lane >> 3;                 // 0..7 (row within 8-row chunk)
  const int lc = (lane & 7) << 3;           // element col 0,8,...,56

  const bf16_t* Ag = A  + (size_t)m0 * C_DIM;
  const bf16_t* Bg = WT + (size_t)n0 * C_DIM;

  f32x4 acc[4][4] = {};

  // stage K-tile kt into LDS buffer d (8 gload16 per thread)
  #define STAGE_QKV(D, KT)                                                   \
    {                                                                        \
      const int k0_ = (KT) * 64;                                             \
      _Pragma("unroll")                                                      \
      for (int j = 0; j < 4; ++j) {                                          \
        const int row_ = wave * 32 + j * 8;                                  \
        gload16(Ag + (size_t)(row_ + lr) * C_DIM + k0_ + lc, &As[D][row_ * 64]); \
        gload16(Bg + (size_t)(row_ + lr) * C_DIM + k0_ + lc, &Bs[D][row_ * 64]); \
      }                                                                      \
    }

  #define COMPUTE_QKV(D)                                                     \
    _Pragma("unroll")                                                        \
    for (int c = 0; c < 2; ++c) {                                            \
      bf16x8 af[4], bfr[4];                                                  \
      _Pragma("unroll")                                                      \
      for (int mt = 0; mt < 4; ++mt)                                         \
        af[mt] = *(const bf16x8*)&As[D][(ww * 64 + mt * 16 + lid) * 64 + c * 32 + quad * 8]; \
      _Pragma("unroll")                                                      \
      for (int nt = 0; nt < 4; ++nt)                                         \
        bfr[nt] = *(const bf16x8*)&Bs[D][(wc * 64 + nt * 16 + lid) * 64 + c * 32 + quad * 8]; \
      _Pragma("unroll")                                                      \
      for (int mt = 0; mt < 4; ++mt)                                         \
        _Pragma("unroll")                                                    \
        for (int nt = 0; nt < 4; ++nt)                                       \
          acc[mt][nt] = __builtin_amdgcn_mfma_f32_16x16x32_bf16(af[mt], bfr[nt], acc[mt][nt], 0, 0, 0); \
    }

  STAGE_QKV(0, 0)
  STAGE_QKV(1, 1)

  #pragma unroll 1
  for (int kt = 0; kt < 16; ++kt) {
    const int d = kt & 1;
    if (kt < 15) { VMCNT(8) } else { VMCNT(0) }
    SBAR()                       // all waves' kt-tile loads landed
    if (d == 0) { COMPUTE_QKV(0) } else { COMPUTE_QKV(1) }
    SBAR()                       // all waves done reading buf d
    if (kt + 2 < 16) {
      if (d == 0) { STAGE_QKV(0, kt + 2) } else { STAGE_QKV(1, kt + 2) }
    }
  }

  // wsel is block-uniform (each 128-col block lies inside one of Q/K/V)
  const int wsel = n0 >> 10;
  const float qs = (wsel == 0) ? QSCALE : 1.0f;
  #pragma unroll
  for (int mt = 0; mt < 4; ++mt) {
    #pragma unroll
    for (int nt = 0; nt < 4; ++nt) {
      const int row0 = m0 + ww * 64 + mt * 16 + quad * 4;
      const int col = n0 + wc * 64 + nt * 16 + lid;
      const int h = (col >> 6) & 15, dd = col & 63;
      if (wsel == 2) {
        bf16x4_t pv;
        #pragma unroll
        for (int r = 0; r < 4; ++r) pv[r] = (bf16_t)acc[mt][nt][r];
        const int b = row0 >> 11, s = row0 & 2047;
        *(bf16x4_t*)&VT[((size_t)(b * NHEAD + h) * HS_DIM + dd) * S_LEN + s] = pv;
      } else {
        bf16_t* dst = (wsel == 0 ? Q : K);
        #pragma unroll
        for (int r = 0; r < 4; ++r)
          dst[(size_t)(row0 + r) * C_DIM + h * HS_DIM + dd] = (bf16_t)(acc[mt][nt][r] * qs);
      }
    }
  }
}

// ---------------------------------------------------------------------------
// Flash attention (causal), swapped-QK^T 32x32 structure, diagonal-paired
// (R11, unchanged).
// ---------------------------------------------------------------------------
#define PACK_GROUP(SV, BASE, FR)                                         \
  {                                                                      \
    unsigned int w0 = pk2(SV[BASE + 0], SV[BASE + 1]);                   \
    unsigned int w1 = pk2(SV[BASE + 2], SV[BASE + 3]);                   \
    unsigned int w2 = pk2(SV[BASE + 4], SV[BASE + 5]);                   \
    unsigned int w3 = pk2(SV[BASE + 6], SV[BASE + 7]);                   \
    auto sA = __builtin_amdgcn_permlane32_swap(w0, w2, false, false);    \
    auto sB = __builtin_amdgcn_permlane32_swap(w1, w3, false, false);    \
    FR.u[0] = sA[0]; FR.u[2] = sA[1];                                    \
    FR.u[1] = sB[0]; FR.u[3] = sB[1];                                    \
  }

union PFrag { bf16x8 v; unsigned int u[4]; };

__global__ __launch_bounds__(256, 2) void flash_attn_kernel(
    const bf16_t* __restrict__ Q,   // [8192,1024] (pre-scaled by QSCALE)
    const bf16_t* __restrict__ Kb,  // [8192,1024]
    const bf16_t* __restrict__ VT,  // [64,64,2048]
    bf16_t* __restrict__ O) {       // [8192,1024]
  __shared__ __align__(16) bf16_t Ks[2][64][64];
  __shared__ __align__(16) bf16_t Vs[2][64][64];
  const int id = blockIdx.x;
  const int bh = id & 63;                    // id%8 == bh%8 -> XCD locality
  const int bx = id >> 6;                    // 0..7
  const int b = bh >> 4, h = bh & 15;
  const int rb = b * S_LEN;
  const int tid = threadIdx.x;
  const int wave = tid >> 6, lane = tid & 63;
  const int l31 = lane & 31, hi = lane >> 5;

  // staging coords: 256 thr x 16B covers 32 rows x 128B per pass (2 passes)
  const int srow = tid >> 3;                 // 0..31
  const int scol = (tid & 7) << 3;           // element col 0,8,...,56
  const int swcol = scol ^ ((srow & 7) << 3);// XOR-swizzled store col
  const int rsw = (lane & 7) << 3;           // read swizzle term

  const bf16_t* kbase = Kb + (size_t)(rb + srow) * C_DIM + h * HS_DIM + scol;
  const bf16_t* vbase = VT + ((size_t)bh * HS_DIM + srow) * S_LEN + scol;

  #pragma unroll 1
  for (int phase = 0; phase < 2; ++phase) {
    const int s0 = (phase == 0 ? (15 - bx) : bx) * 128;
    const int qw = s0 + wave * 32;           // this wave's first q row

    // Q fragments (B-operand): col q = l31, chunk c: d = c*16 + hi*8 + j
    bf16x8 qfrag[4];
    {
      const bf16_t* qp = Q + (size_t)(rb + qw + l31) * C_DIM + h * HS_DIM + hi * 8;
      #pragma unroll
      for (int c = 0; c < 4; ++c) qfrag[c] = *(const bf16x8*)(qp + c * 16);
    }

    f32x16 oacc0 = {}, oacc1 = {};   // d-tiles 0 (d=l31) and 1 (d=32+l31)
    float m_i = -INFINITY, l_i = 0.f;
    const int nIter = (s0 >> 6) + 2;

    // Prolog: stage tile 0 -> buffer 0
    {
      uint4 k0 = *(const uint4*)(kbase);
      uint4 k1 = *(const uint4*)(kbase + 32 * C_DIM);
      uint4 v0 = *(const uint4*)(vbase);
      uint4 v1 = *(const uint4*)(vbase + 32 * S_LEN);
      *(uint4*)&Ks[0][srow][swcol]      = k0;
      *(uint4*)&Ks[0][srow + 32][swcol] = k1;
      *(uint4*)&Vs[0][srow][swcol]      = v0;
      *(uint4*)&Vs[0][srow + 32][swcol] = v1;
    }
    __syncthreads();

    for (int i = 0; i < nIter; ++i) {
      const int pb = i & 1;
      const int t0 = i << 6;

      // register prefetch of next tile (overlaps compute)
      uint4 k0r, k1r, v0r, v1r;
      const bool haveNext = (i + 1 < nIter);
      if (haveNext) {
        const bf16_t* kp = kbase + (size_t)(t0 + 64) * C_DIM;
        const bf16_t* vp = vbase + (t0 + 64);
        k0r = *(const uint4*)(kp);
        k1r = *(const uint4*)(kp + 32 * C_DIM);
        v0r = *(const uint4*)(vp);
        v1r = *(const uint4*)(vp + 32 * S_LEN);
      }

      if (t0 < qw + 32) {   // wave-uniform causal skip
        // ---- QK^T (swapped): sacc[t][q], t-tiles 0/1 ----
        f32x16 sa0 = {}, sa1 = {};
        __builtin_amdgcn_s_setprio(1);
        #pragma unroll
        for (int c = 0; c < 4; ++c) {
          const int col = (c * 16 + hi * 8) ^ rsw;
          bf16x8 kf0 = *(const bf16x8*)&Ks[pb][l31][col];
          bf16x8 kf1 = *(const bf16x8*)&Ks[pb][l31 + 32][col];
          sa0 = __builtin_amdgcn_mfma_f32_32x32x16_bf16(kf0, qfrag[c], sa0, 0, 0, 0);
          sa1 = __builtin_amdgcn_mfma_f32_32x32x16_bf16(kf1, qfrag[c], sa1, 0, 0, 0);
        }
        __builtin_amdgcn_s_setprio(0);

        // causal mask (diag tiles only; scores pre-scaled via Q)
        const bool diag = (t0 + 63 > qw);
        if (diag) {
          const int qg = qw + l31;
          #pragma unroll
          for (int r = 0; r < 16; ++r) {
            const int tr = (r & 3) + 8 * (r >> 2) + 4 * hi;
            if (t0 + tr > qg)      sa0[r] = -INFINITY;
            if (t0 + 32 + tr > qg) sa1[r] = -INFINITY;
          }
        }

        // in-register row max + cross-half combine
        float pmax = -INFINITY;
        #pragma unroll
        for (int r = 0; r < 16; ++r) pmax = fmaxf(pmax, fmaxf(sa0[r], sa1[r]));
        pmax = fmaxf(pmax, __shfl_xor(pmax, 32));

        // defer-max rescale (T13): only rescale when max grew by > 8 (exp2 dom)
        if (!__all(pmax <= m_i + 8.f)) {
          const float mnew = fmaxf(m_i, pmax);
          const float alpha = exp2f(m_i - mnew);
          m_i = mnew;
          l_i *= alpha;
          #pragma unroll
          for (int r = 0; r < 16; ++r) {
            const float av = __shfl(alpha, (r & 3) + 8 * (r >> 2) + 4 * hi);
            oacc0[r] *= av;
            oacc1[r] *= av;
          }
        }

        // P = exp2(s - m), row sum
        float rsum = 0.f;
        #pragma unroll
        for (int r = 0; r < 16; ++r) {
          const float p0 = exp2f(sa0[r] - m_i);
          const float p1 = exp2f(sa1[r] - m_i);
          sa0[r] = p0; sa1[r] = p1;
          rsum += p0 + p1;
        }
        rsum += __shfl_xor(rsum, 32);
        l_i += rsum;

        // pack P -> 4 A-frags (ks = t/16) via cvt-pk + permlane32_swap (T12)
        PFrag pf[4];
        PACK_GROUP(sa0, 0, pf[0])
        PACK_GROUP(sa0, 8, pf[1])
        PACK_GROUP(sa1, 0, pf[2])
        PACK_GROUP(sa1, 8, pf[3])

        // ---- PV ----
        __builtin_amdgcn_s_setprio(1);
        #pragma unroll
        for (int ks = 0; ks < 4; ++ks) {
          const int col = (ks * 16 + hi * 8) ^ rsw;
          bf16x8 vf0 = *(const bf16x8*)&Vs[pb][l31][col];
          bf16x8 vf1 = *(const bf16x8*)&Vs[pb][l31 + 32][col];
          oacc0 = __builtin_amdgcn_mfma_f32_32x32x16_bf16(pf[ks].v, vf0, oacc0, 0, 0, 0);
          oacc1 = __builtin_amdgcn_mfma_f32_32x32x16_bf16(pf[ks].v, vf1, oacc1, 0, 0, 0);
        }
        __builtin_amdgcn_s_setprio(0);
      }

      // write prefetched tile into the idle buffer; single barrier/iter
      if (haveNext) {
        *(uint4*)&Ks[1 - pb][srow][swcol]      = k0r;
        *(uint4*)&Ks[1 - pb][srow + 32][swcol] = k1r;
        *(uint4*)&Vs[1 - pb][srow][swcol]      = v0r;
        *(uint4*)&Vs[1 - pb][srow + 32][swcol] = v1r;
        __syncthreads();
      }
    }

    // epilogue: O = oacc / l  (broadcast 1/l from lane q to row layout)
    const float linv = 1.f / l_i;
    #pragma unroll
    for (int r = 0; r < 16; ++r) {
      const int qrow = (r & 3) + 8 * (r >> 2) + 4 * hi;
      const float inv = __shfl(linv, qrow);
      const int row = rb + qw + qrow;
      O[(size_t)row * C_DIM + h * HS_DIM + l31]      = (bf16_t)(oacc0[r] * inv);
      O[(size_t)row * C_DIM + h * HS_DIM + 32 + l31] = (bf16_t)(oacc1[r] * inv);
    }

    __syncthreads();   // LDS handoff to next phase's prolog
  }
}

// ---------------------------------------------------------------------------
// Output projection: out = O @ WpT^T + bp (fp32 stores).
// Counted-vmcnt double-buffered pipeline (R12).
// ---------------------------------------------------------------------------
__global__ __launch_bounds__(256) void gemm_out128(
    const bf16_t* __restrict__ A,    // [8192,1024] O (bf16)
    const bf16_t* __restrict__ Bw,   // [1024,1024] Wp (bf16)
    const float* __restrict__ bias,  // [1024]
    float* __restrict__ out) {       // [8192,1024] fp32
  __shared__ __align__(16) bf16_t As[2][128 * 64];
  __shared__ __align__(16) bf16_t Bs[2][128 * 64];
  const int m0 = blockIdx.x * 128;
  const int n0 = blockIdx.y * 128;
  const int tid = threadIdx.x;
  const int wave = tid >> 6, lane = tid & 63, quad = lane >> 4, lid = lane & 15;
  const int ww = wave >> 1, wc = wave & 1;
  const int lr = lane >> 3;
  const int lc = (lane & 7) << 3;

  const bf16_t* Ag = A  + (size_t)m0 * C_DIM;
  const bf16_t* Bg = Bw + (size_t)n0 * C_DIM;

  f32x4 acc[4][4] = {};

  #define STAGE_OUT(D, KT)                                                   \
    {                                                                        \
      const int k0_ = (KT) * 64;                                             \
      _Pragma("unroll")                                                      \
      for (int j = 0; j < 4; ++j) {                                          \
        const int row_ = wave * 32 + j * 8;                                  \
        gload16(Ag + (size_t)(row_ + lr) * C_DIM + k0_ + lc, &As[D][row_ * 64]); \
        gload16(Bg + (size_t)(row_ + lr) * C_DIM + k0_ + lc, &Bs[D][row_ * 64]); \
      }                                                                      \
    }

  STAGE_OUT(0, 0)
  STAGE_OUT(1, 1)

  #pragma unroll 1
  for (int kt = 0; kt < 16; ++kt) {
    const int d = kt & 1;
    if (kt < 15) { VMCNT(8) } else { VMCNT(0) }
    SBAR()
    #pragma unroll
    for (int c = 0; c < 2; ++c) {
      bf16x8 af[4], bfr[4];
      #pragma unroll
      for (int mt = 0; mt < 4; ++mt)
        af[mt] = *(const bf16x8*)&As[d][(ww * 64 + mt * 16 + lid) * 64 + c * 32 + quad * 8];
      #pragma unroll
      for (int nt = 0; nt < 4; ++nt)
        bfr[nt] = *(const bf16x8*)&Bs[d][(wc * 64 + nt * 16 + lid) * 64 + c * 32 + quad * 8];
      #pragma unroll
      for (int mt = 0; mt < 4; ++mt)
        #pragma unroll
        for (int nt = 0; nt < 4; ++nt)
          acc[mt][nt] = __builtin_amdgcn_mfma_f32_16x16x32_bf16(af[mt], bfr[nt], acc[mt][nt], 0, 0, 0);
    }
    SBAR()
    if (kt + 2 < 16) {
      if (d == 0) { STAGE_OUT(0, kt + 2) } else { STAGE_OUT(1, kt + 2) }
    }
  }

  #pragma unroll
  for (int mt = 0; mt < 4; ++mt) {
    #pragma unroll
    for (int nt = 0; nt < 4; ++nt) {
      #pragma unroll
      for (int r = 0; r < 4; ++r) {
        const int row = m0 + ww * 64 + mt * 16 + quad * 4 + r;
        const int col = n0 + wc * 64 + nt * 16 + lid;
        out[(size_t)row * C_DIM + col] = acc[mt][nt][r] + bias[col];
      }
    }
  }
}

// ---------------------------------------------------------------------------
extern "C" void kernel_launch(void* const* d_in, const int* in_sizes, int n_in,
                              void* d_out, int out_size, void* d_ws, size_t ws_size,
                              hipStream_t stream) {
  const float *x, *Wq, *Wk, *Wv, *Wp, *bp;
  if (in_sizes[0] == MROWS * C_DIM) {            // dict order (confirmed)
    x  = (const float*)d_in[0];
    Wq = (const float*)d_in[1];
    Wk = (const float*)d_in[2];
    Wv = (const float*)d_in[3];
    Wp = (const float*)d_in[4];
    bp = (const float*)d_in[5];
  } else {                                        // key-sorted hedge
    Wk = (const float*)d_in[0];
    Wp = (const float*)d_in[1];
    Wq = (const float*)d_in[2];
    Wv = (const float*)d_in[3];
    bp = (const float*)d_in[4];
    x  = (const float*)d_in[5];
  }
  float* out = (float*)d_out;

  // ws = 64 MB: [Ob 16MB (WT aliases its first 6MB; dead before flash;
  //              WpT aliases Qb after flash)] [Qb 16MB][Kb 16MB][VTb 16MB]
  // xb (bf16 x) lives in the first 16MB of d_out (dead before gemm_out writes).
  const size_t NB = (size_t)MROWS * C_DIM;   // 8 M elements
  bf16_t* ws  = (bf16_t*)d_ws;
  bf16_t* Ob  = ws;            // [8192,1024]
  bf16_t* WT  = ws;            // [3072,1024] — aliases Ob, dead after QKV GEMM
  bf16_t* Qb  = ws + NB;       // [8192,1024]
  bf16_t* Kb  = Qb + NB;       // [8192,1024]
  bf16_t* VTb = Kb + NB;       // [64,64,2048]
  bf16_t* WpT = Qb;            // [1024,1024] — aliases Qb, written after flash
  bf16_t* xb  = (bf16_t*)d_out;// [8192,1024] — scratch in output buffer

  pack_w_kernel<<<dim3(16, 16, 3), 256, 0, stream>>>(Wq, Wk, Wv, WT);
  convert_bf16<<<dim3(4096), 256, 0, stream>>>(x, xb);
  gemm_qkv128<<<dim3(64, 24), 256, 0, stream>>>(xb, WT, Qb, Kb, VTb);
  flash_attn_kernel<<<dim3(512), 256, 0, stream>>>(Qb, Kb, VTb, Ob);
  convert_bf16<<<dim3(512), 256, 0, stream>>>(Wp, WpT);
  gemm_out128<<<dim3(64, 8), 256, 0, stream>>>(Ob, WpT, bp, out);
}

// Round 5
// 263.036 us; speedup vs baseline: 1.8730x; 1.0547x over previous
//
#include <hip/hip_runtime.h>
#include <hip/hip_bf16.h>
#include <math.h>

// B=4, S=2048, C=1024, H=16, HS=64
// Inputs (fp32, dict order): x[4,2048,1024], Wq/Wk/Wv[16,1024,64],
//                            Wp[1024,1024], bp[1024]
// Output: FP32 [4,2048,1024]
// R13: GEMM iteration reordered: frag-preload (all 16 ds_read_b128 -> VGPR)
//      -> lgkmcnt(0) -> barrier -> STAGE(kt+2) issued BEFORE the 32-MFMA
//      block. Prefetch distance grows from ~1/3 iter to ~1 full iter; MFMA
//      covers load-issue VALU. Same 2-buffer/2-barrier skeleton as R12
//      (WAR-safe by program order). Flash/pack/convert unchanged from R12.

typedef __bf16 bf16_t;
typedef __bf16 bf16x4_t __attribute__((ext_vector_type(4)));
typedef __bf16 bf16x8 __attribute__((ext_vector_type(8)));
typedef __bf16 bf16x2 __attribute__((ext_vector_type(2)));
typedef float f32x4 __attribute__((ext_vector_type(4)));
typedef float f32x16 __attribute__((ext_vector_type(16)));

#define S_LEN 2048
#define C_DIM 1024
#define NHEAD 16
#define HS_DIM 64
#define MROWS 8192   // B*S
#define QSCALE 0.18033688011112042f  // 0.125 * log2(e)

__device__ __forceinline__ void cvt8(bf16_t* dst, const float* __restrict__ src) {
  const float4 a = *(const float4*)src;
  const float4 b = *(const float4*)(src + 4);
  bf16x8 v;
  v[0] = (bf16_t)a.x; v[1] = (bf16_t)a.y; v[2] = (bf16_t)a.z; v[3] = (bf16_t)a.w;
  v[4] = (bf16_t)b.x; v[5] = (bf16_t)b.y; v[6] = (bf16_t)b.z; v[7] = (bf16_t)b.w;
  *(bf16x8*)dst = v;
}

// pack two f32 -> one u32 of 2xbf16 (compiler fuses to v_cvt_pk_bf16_f32; m240)
__device__ __forceinline__ unsigned int pk2(float a, float b) {
  union { bf16x2 h; unsigned int u; } t;
  t.h[0] = (bf16_t)a;
  t.h[1] = (bf16_t)b;
  return t.u;
}

// async global->LDS, 16B per lane; LDS dest = wave-uniform base + lane*16
__device__ __forceinline__ void gload16(const bf16_t* g, bf16_t* l) {
  __builtin_amdgcn_global_load_lds(
      (const __attribute__((address_space(1))) unsigned int*)(const void*)g,
      (__attribute__((address_space(3))) unsigned int*)(void*)l,
      16, 0, 0);
}

#define SBAR()  { __builtin_amdgcn_sched_barrier(0); \
                  __builtin_amdgcn_s_barrier();      \
                  __builtin_amdgcn_sched_barrier(0); }
#define VMCNT(N) { asm volatile("s_waitcnt vmcnt(" #N ")" ::: "memory"); \
                   __builtin_amdgcn_sched_barrier(0); }
#define LGKMCNT0() { asm volatile("s_waitcnt lgkmcnt(0)" ::: "memory"); \
                     __builtin_amdgcn_sched_barrier(0); }

// ---------------------------------------------------------------------------
// Elementwise fp32 -> bf16 convert (8 elems/thread). Used for x and Wp.
// ---------------------------------------------------------------------------
__global__ __launch_bounds__(256) void convert_bf16(
    const float* __restrict__ src, bf16_t* __restrict__ dst) {
  const size_t i = ((size_t)blockIdx.x * 256 + threadIdx.x) * 8;
  cvt8(dst + i, src + i);
}

// ---------------------------------------------------------------------------
// Pack Wq,Wk,Wv (fp32 [16,1024,64]) -> bf16 WT[3072,1024]:
// WT[wsel*1024+h*64+d][c] = W[h][c][d].
// ---------------------------------------------------------------------------
__global__ __launch_bounds__(256) void pack_w_kernel(
    const float* __restrict__ Wq, const float* __restrict__ Wk,
    const float* __restrict__ Wv, bf16_t* __restrict__ WT) {
  __shared__ __align__(16) float tile[64][68];
  const int wsel = blockIdx.z;
  const int h = blockIdx.y;
  const int c0 = blockIdx.x * 64;
  const float* W = (wsel == 0 ? Wq : (wsel == 1 ? Wk : Wv)) + (size_t)h * (C_DIM * HS_DIM);
  const int tr = threadIdx.x >> 2;          // 0..63 (c-row within tile)
  const int tc = (threadIdx.x & 3) << 4;    // 0,16,32,48
  #pragma unroll
  for (int j = 0; j < 16; j += 4)
    *(float4*)&tile[tr][tc + j] = *(const float4*)(W + (size_t)(c0 + tr) * HS_DIM + tc + j);
  __syncthreads();
  const int d = threadIdx.x >> 2;           // 0..63
  const int cb = (threadIdx.x & 3) << 4;    // 0,16,32,48
  bf16_t* dst = WT + ((size_t)(wsel * 1024 + h * 64 + d)) * C_DIM + c0 + cb;
  #pragma unroll
  for (int i = 0; i < 16; ++i) dst[i] = (bf16_t)tile[cb + i][d];
}

// ---------------------------------------------------------------------------
// QKV projection: xb[8192,1024](bf16) x WT[3072,1024](bf16)^T.
// R13 pipeline: frag-preload -> barrier -> early STAGE(kt+2) -> MFMA.
// 128x128x64 tiles, 4 waves 2x2, 4x4 accs/wave. Q pre-scaled by QSCALE.
// ---------------------------------------------------------------------------
__global__ __launch_bounds__(256, 2) void gemm_qkv128(
    const bf16_t* __restrict__ A, const bf16_t* __restrict__ WT,
    bf16_t* __restrict__ Q, bf16_t* __restrict__ K, bf16_t* __restrict__ VT) {
  __shared__ __align__(16) bf16_t As[2][128 * 64];
  __shared__ __align__(16) bf16_t Bs[2][128 * 64];
  const int m0 = blockIdx.x * 128;
  const int n0 = blockIdx.y * 128;
  const int tid = threadIdx.x;
  const int wave = tid >> 6, lane = tid & 63, quad = lane >> 4, lid = lane & 15;
  const int ww = wave >> 1, wc = wave & 1;
  const int lr = lane >> 3;                 // 0..7 (row within 8-row chunk)
  const int lc = (lane & 7) << 3;           // element col 0,8,...,56

  const bf16_t* Ag = A  + (size_t)m0 * C_DIM;
  const bf16_t* Bg = WT + (size_t)n0 * C_DIM;

  f32x4 acc[4][4] = {};

  #define STAGE_QKV(D, KT)                                                   \
    {                                                                        \
      const int k0_ = (KT) * 64;                                             \
      _Pragma("unroll")                                                      \
      for (int j = 0; j < 4; ++j) {                                          \
        const int row_ = wave * 32 + j * 8;                                  \
        gload16(Ag + (size_t)(row_ + lr) * C_DIM + k0_ + lc, &As[D][row_ * 64]); \
        gload16(Bg + (size_t)(row_ + lr) * C_DIM + k0_ + lc, &Bs[D][row_ * 64]); \
      }                                                                      \
    }

  STAGE_QKV(0, 0)
  STAGE_QKV(1, 1)

  #pragma unroll 1
  for (int kt = 0; kt < 16; ++kt) {
    const int d = kt & 1;
    if (kt < 15) { VMCNT(8) } else { VMCNT(0) }
    SBAR()                       // all waves' kt-tile loads landed

    // frag-preload: consume buf d entirely into VGPRs
    const bf16_t* Asd = As[d];
    const bf16_t* Bsd = Bs[d];
    bf16x8 af[2][4], bfr[2][4];
    #pragma unroll
    for (int c = 0; c < 2; ++c) {
      #pragma unroll
      for (int mt = 0; mt < 4; ++mt)
        af[c][mt] = *(const bf16x8*)&Asd[(ww * 64 + mt * 16 + lid) * 64 + c * 32 + quad * 8];
      #pragma unroll
      for (int nt = 0; nt < 4; ++nt)
        bfr[c][nt] = *(const bf16x8*)&Bsd[(wc * 64 + nt * 16 + lid) * 64 + c * 32 + quad * 8];
    }
    LGKMCNT0()                   // this wave's ds_reads retired (rule #18)
    SBAR()                       // all waves done reading buf d

    // early stage: issue kt+2 into the just-freed buffer BEFORE the MFMAs
    if (kt + 2 < 16) {
      if (d == 0) { STAGE_QKV(0, kt + 2) } else { STAGE_QKV(1, kt + 2) }
    }
    __builtin_amdgcn_sched_barrier(0);   // pin: loads issue before MFMA block

    #pragma unroll
    for (int c = 0; c < 2; ++c)
      #pragma unroll
      for (int mt = 0; mt < 4; ++mt)
        #pragma unroll
        for (int nt = 0; nt < 4; ++nt)
          acc[mt][nt] = __builtin_amdgcn_mfma_f32_16x16x32_bf16(af[c][mt], bfr[c][nt], acc[mt][nt], 0, 0, 0);
  }

  // wsel is block-uniform (each 128-col block lies inside one of Q/K/V)
  const int wsel = n0 >> 10;
  const float qs = (wsel == 0) ? QSCALE : 1.0f;
  #pragma unroll
  for (int mt = 0; mt < 4; ++mt) {
    #pragma unroll
    for (int nt = 0; nt < 4; ++nt) {
      const int row0 = m0 + ww * 64 + mt * 16 + quad * 4;
      const int col = n0 + wc * 64 + nt * 16 + lid;
      const int h = (col >> 6) & 15, dd = col & 63;
      if (wsel == 2) {
        bf16x4_t pv;
        #pragma unroll
        for (int r = 0; r < 4; ++r) pv[r] = (bf16_t)acc[mt][nt][r];
        const int b = row0 >> 11, s = row0 & 2047;
        *(bf16x4_t*)&VT[((size_t)(b * NHEAD + h) * HS_DIM + dd) * S_LEN + s] = pv;
      } else {
        bf16_t* dst = (wsel == 0 ? Q : K);
        #pragma unroll
        for (int r = 0; r < 4; ++r)
          dst[(size_t)(row0 + r) * C_DIM + h * HS_DIM + dd] = (bf16_t)(acc[mt][nt][r] * qs);
      }
    }
  }
}

// ---------------------------------------------------------------------------
// Flash attention (causal), swapped-QK^T 32x32 structure, diagonal-paired
// (R11, unchanged).
// ---------------------------------------------------------------------------
#define PACK_GROUP(SV, BASE, FR)                                         \
  {                                                                      \
    unsigned int w0 = pk2(SV[BASE + 0], SV[BASE + 1]);                   \
    unsigned int w1 = pk2(SV[BASE + 2], SV[BASE + 3]);                   \
    unsigned int w2 = pk2(SV[BASE + 4], SV[BASE + 5]);                   \
    unsigned int w3 = pk2(SV[BASE + 6], SV[BASE + 7]);                   \
    auto sA = __builtin_amdgcn_permlane32_swap(w0, w2, false, false);    \
    auto sB = __builtin_amdgcn_permlane32_swap(w1, w3, false, false);    \
    FR.u[0] = sA[0]; FR.u[2] = sA[1];                                    \
    FR.u[1] = sB[0]; FR.u[3] = sB[1];                                    \
  }

union PFrag { bf16x8 v; unsigned int u[4]; };

__global__ __launch_bounds__(256, 2) void flash_attn_kernel(
    const bf16_t* __restrict__ Q,   // [8192,1024] (pre-scaled by QSCALE)
    const bf16_t* __restrict__ Kb,  // [8192,1024]
    const bf16_t* __restrict__ VT,  // [64,64,2048]
    bf16_t* __restrict__ O) {       // [8192,1024]
  __shared__ __align__(16) bf16_t Ks[2][64][64];
  __shared__ __align__(16) bf16_t Vs[2][64][64];
  const int id = blockIdx.x;
  const int bh = id & 63;                    // id%8 == bh%8 -> XCD locality
  const int bx = id >> 6;                    // 0..7
  const int b = bh >> 4, h = bh & 15;
  const int rb = b * S_LEN;
  const int tid = threadIdx.x;
  const int wave = tid >> 6, lane = tid & 63;
  const int l31 = lane & 31, hi = lane >> 5;

  // staging coords: 256 thr x 16B covers 32 rows x 128B per pass (2 passes)
  const int srow = tid >> 3;                 // 0..31
  const int scol = (tid & 7) << 3;           // element col 0,8,...,56
  const int swcol = scol ^ ((srow & 7) << 3);// XOR-swizzled store col
  const int rsw = (lane & 7) << 3;           // read swizzle term

  const bf16_t* kbase = Kb + (size_t)(rb + srow) * C_DIM + h * HS_DIM + scol;
  const bf16_t* vbase = VT + ((size_t)bh * HS_DIM + srow) * S_LEN + scol;

  #pragma unroll 1
  for (int phase = 0; phase < 2; ++phase) {
    const int s0 = (phase == 0 ? (15 - bx) : bx) * 128;
    const int qw = s0 + wave * 32;           // this wave's first q row

    // Q fragments (B-operand): col q = l31, chunk c: d = c*16 + hi*8 + j
    bf16x8 qfrag[4];
    {
      const bf16_t* qp = Q + (size_t)(rb + qw + l31) * C_DIM + h * HS_DIM + hi * 8;
      #pragma unroll
      for (int c = 0; c < 4; ++c) qfrag[c] = *(const bf16x8*)(qp + c * 16);
    }

    f32x16 oacc0 = {}, oacc1 = {};   // d-tiles 0 (d=l31) and 1 (d=32+l31)
    float m_i = -INFINITY, l_i = 0.f;
    const int nIter = (s0 >> 6) + 2;

    // Prolog: stage tile 0 -> buffer 0
    {
      uint4 k0 = *(const uint4*)(kbase);
      uint4 k1 = *(const uint4*)(kbase + 32 * C_DIM);
      uint4 v0 = *(const uint4*)(vbase);
      uint4 v1 = *(const uint4*)(vbase + 32 * S_LEN);
      *(uint4*)&Ks[0][srow][swcol]      = k0;
      *(uint4*)&Ks[0][srow + 32][swcol] = k1;
      *(uint4*)&Vs[0][srow][swcol]      = v0;
      *(uint4*)&Vs[0][srow + 32][swcol] = v1;
    }
    __syncthreads();

    for (int i = 0; i < nIter; ++i) {
      const int pb = i & 1;
      const int t0 = i << 6;

      // register prefetch of next tile (overlaps compute)
      uint4 k0r, k1r, v0r, v1r;
      const bool haveNext = (i + 1 < nIter);
      if (haveNext) {
        const bf16_t* kp = kbase + (size_t)(t0 + 64) * C_DIM;
        const bf16_t* vp = vbase + (t0 + 64);
        k0r = *(const uint4*)(kp);
        k1r = *(const uint4*)(kp + 32 * C_DIM);
        v0r = *(const uint4*)(vp);
        v1r = *(const uint4*)(vp + 32 * S_LEN);
      }

      if (t0 < qw + 32) {   // wave-uniform causal skip
        // ---- QK^T (swapped): sacc[t][q], t-tiles 0/1 ----
        f32x16 sa0 = {}, sa1 = {};
        __builtin_amdgcn_s_setprio(1);
        #pragma unroll
        for (int c = 0; c < 4; ++c) {
          const int col = (c * 16 + hi * 8) ^ rsw;
          bf16x8 kf0 = *(const bf16x8*)&Ks[pb][l31][col];
          bf16x8 kf1 = *(const bf16x8*)&Ks[pb][l31 + 32][col];
          sa0 = __builtin_amdgcn_mfma_f32_32x32x16_bf16(kf0, qfrag[c], sa0, 0, 0, 0);
          sa1 = __builtin_amdgcn_mfma_f32_32x32x16_bf16(kf1, qfrag[c], sa1, 0, 0, 0);
        }
        __builtin_amdgcn_s_setprio(0);

        // causal mask (diag tiles only; scores pre-scaled via Q)
        const bool diag = (t0 + 63 > qw);
        if (diag) {
          const int qg = qw + l31;
          #pragma unroll
          for (int r = 0; r < 16; ++r) {
            const int tr = (r & 3) + 8 * (r >> 2) + 4 * hi;
            if (t0 + tr > qg)      sa0[r] = -INFINITY;
            if (t0 + 32 + tr > qg) sa1[r] = -INFINITY;
          }
        }

        // in-register row max + cross-half combine
        float pmax = -INFINITY;
        #pragma unroll
        for (int r = 0; r < 16; ++r) pmax = fmaxf(pmax, fmaxf(sa0[r], sa1[r]));
        pmax = fmaxf(pmax, __shfl_xor(pmax, 32));

        // defer-max rescale (T13): only rescale when max grew by > 8 (exp2 dom)
        if (!__all(pmax <= m_i + 8.f)) {
          const float mnew = fmaxf(m_i, pmax);
          const float alpha = exp2f(m_i - mnew);
          m_i = mnew;
          l_i *= alpha;
          #pragma unroll
          for (int r = 0; r < 16; ++r) {
            const float av = __shfl(alpha, (r & 3) + 8 * (r >> 2) + 4 * hi);
            oacc0[r] *= av;
            oacc1[r] *= av;
          }
        }

        // P = exp2(s - m), row sum
        float rsum = 0.f;
        #pragma unroll
        for (int r = 0; r < 16; ++r) {
          const float p0 = exp2f(sa0[r] - m_i);
          const float p1 = exp2f(sa1[r] - m_i);
          sa0[r] = p0; sa1[r] = p1;
          rsum += p0 + p1;
        }
        rsum += __shfl_xor(rsum, 32);
        l_i += rsum;

        // pack P -> 4 A-frags (ks = t/16) via cvt-pk + permlane32_swap (T12)
        PFrag pf[4];
        PACK_GROUP(sa0, 0, pf[0])
        PACK_GROUP(sa0, 8, pf[1])
        PACK_GROUP(sa1, 0, pf[2])
        PACK_GROUP(sa1, 8, pf[3])

        // ---- PV ----
        __builtin_amdgcn_s_setprio(1);
        #pragma unroll
        for (int ks = 0; ks < 4; ++ks) {
          const int col = (ks * 16 + hi * 8) ^ rsw;
          bf16x8 vf0 = *(const bf16x8*)&Vs[pb][l31][col];
          bf16x8 vf1 = *(const bf16x8*)&Vs[pb][l31 + 32][col];
          oacc0 = __builtin_amdgcn_mfma_f32_32x32x16_bf16(pf[ks].v, vf0, oacc0, 0, 0, 0);
          oacc1 = __builtin_amdgcn_mfma_f32_32x32x16_bf16(pf[ks].v, vf1, oacc1, 0, 0, 0);
        }
        __builtin_amdgcn_s_setprio(0);
      }

      // write prefetched tile into the idle buffer; single barrier/iter
      if (haveNext) {
        *(uint4*)&Ks[1 - pb][srow][swcol]      = k0r;
        *(uint4*)&Ks[1 - pb][srow + 32][swcol] = k1r;
        *(uint4*)&Vs[1 - pb][srow][swcol]      = v0r;
        *(uint4*)&Vs[1 - pb][srow + 32][swcol] = v1r;
        __syncthreads();
      }
    }

    // epilogue: O = oacc / l  (broadcast 1/l from lane q to row layout)
    const float linv = 1.f / l_i;
    #pragma unroll
    for (int r = 0; r < 16; ++r) {
      const int qrow = (r & 3) + 8 * (r >> 2) + 4 * hi;
      const float inv = __shfl(linv, qrow);
      const int row = rb + qw + qrow;
      O[(size_t)row * C_DIM + h * HS_DIM + l31]      = (bf16_t)(oacc0[r] * inv);
      O[(size_t)row * C_DIM + h * HS_DIM + 32 + l31] = (bf16_t)(oacc1[r] * inv);
    }

    __syncthreads();   // LDS handoff to next phase's prolog
  }
}

// ---------------------------------------------------------------------------
// Output projection: out = O @ WpT^T + bp (fp32 stores). R13 pipeline.
// ---------------------------------------------------------------------------
__global__ __launch_bounds__(256, 2) void gemm_out128(
    const bf16_t* __restrict__ A,    // [8192,1024] O (bf16)
    const bf16_t* __restrict__ Bw,   // [1024,1024] Wp (bf16)
    const float* __restrict__ bias,  // [1024]
    float* __restrict__ out) {       // [8192,1024] fp32
  __shared__ __align__(16) bf16_t As[2][128 * 64];
  __shared__ __align__(16) bf16_t Bs[2][128 * 64];
  const int m0 = blockIdx.x * 128;
  const int n0 = blockIdx.y * 128;
  const int tid = threadIdx.x;
  const int wave = tid >> 6, lane = tid & 63, quad = lane >> 4, lid = lane & 15;
  const int ww = wave >> 1, wc = wave & 1;
  const int lr = lane >> 3;
  const int lc = (lane & 7) << 3;

  const bf16_t* Ag = A  + (size_t)m0 * C_DIM;
  const bf16_t* Bg = Bw + (size_t)n0 * C_DIM;

  f32x4 acc[4][4] = {};

  #define STAGE_OUT(D, KT)                                                   \
    {                                                                        \
      const int k0_ = (KT) * 64;                                             \
      _Pragma("unroll")                                                      \
      for (int j = 0; j < 4; ++j) {                                          \
        const int row_ = wave * 32 + j * 8;                                  \
        gload16(Ag + (size_t)(row_ + lr) * C_DIM + k0_ + lc, &As[D][row_ * 64]); \
        gload16(Bg + (size_t)(row_ + lr) * C_DIM + k0_ + lc, &Bs[D][row_ * 64]); \
      }                                                                      \
    }

  STAGE_OUT(0, 0)
  STAGE_OUT(1, 1)

  #pragma unroll 1
  for (int kt = 0; kt < 16; ++kt) {
    const int d = kt & 1;
    if (kt < 15) { VMCNT(8) } else { VMCNT(0) }
    SBAR()

    const bf16_t* Asd = As[d];
    const bf16_t* Bsd = Bs[d];
    bf16x8 af[2][4], bfr[2][4];
    #pragma unroll
    for (int c = 0; c < 2; ++c) {
      #pragma unroll
      for (int mt = 0; mt < 4; ++mt)
        af[c][mt] = *(const bf16x8*)&Asd[(ww * 64 + mt * 16 + lid) * 64 + c * 32 + quad * 8];
      #pragma unroll
      for (int nt = 0; nt < 4; ++nt)
        bfr[c][nt] = *(const bf16x8*)&Bsd[(wc * 64 + nt * 16 + lid) * 64 + c * 32 + quad * 8];
    }
    LGKMCNT0()
    SBAR()

    if (kt + 2 < 16) {
      if (d == 0) { STAGE_OUT(0, kt + 2) } else { STAGE_OUT(1, kt + 2) }
    }
    __builtin_amdgcn_sched_barrier(0);

    #pragma unroll
    for (int c = 0; c < 2; ++c)
      #pragma unroll
      for (int mt = 0; mt < 4; ++mt)
        #pragma unroll
        for (int nt = 0; nt < 4; ++nt)
          acc[mt][nt] = __builtin_amdgcn_mfma_f32_16x16x32_bf16(af[c][mt], bfr[c][nt], acc[mt][nt], 0, 0, 0);
  }

  #pragma unroll
  for (int mt = 0; mt < 4; ++mt) {
    #pragma unroll
    for (int nt = 0; nt < 4; ++nt) {
      #pragma unroll
      for (int r = 0; r < 4; ++r) {
        const int row = m0 + ww * 64 + mt * 16 + quad * 4 + r;
        const int col = n0 + wc * 64 + nt * 16 + lid;
        out[(size_t)row * C_DIM + col] = acc[mt][nt][r] + bias[col];
      }
    }
  }
}

// ---------------------------------------------------------------------------
extern "C" void kernel_launch(void* const* d_in, const int* in_sizes, int n_in,
                              void* d_out, int out_size, void* d_ws, size_t ws_size,
                              hipStream_t stream) {
  const float *x, *Wq, *Wk, *Wv, *Wp, *bp;
  if (in_sizes[0] == MROWS * C_DIM) {            // dict order (confirmed)
    x  = (const float*)d_in[0];
    Wq = (const float*)d_in[1];
    Wk = (const float*)d_in[2];
    Wv = (const float*)d_in[3];
    Wp = (const float*)d_in[4];
    bp = (const float*)d_in[5];
  } else {                                        // key-sorted hedge
    Wk = (const float*)d_in[0];
    Wp = (const float*)d_in[1];
    Wq = (const float*)d_in[2];
    Wv = (const float*)d_in[3];
    bp = (const float*)d_in[4];
    x  = (const float*)d_in[5];
  }
  float* out = (float*)d_out;

  // ws = 64 MB: [Ob 16MB (WT aliases its first 6MB; dead before flash;
  //              WpT aliases Qb after flash)] [Qb 16MB][Kb 16MB][VTb 16MB]
  // xb (bf16 x) lives in the first 16MB of d_out (dead before gemm_out writes).
  const size_t NB = (size_t)MROWS * C_DIM;   // 8 M elements
  bf16_t* ws  = (bf16_t*)d_ws;
  bf16_t* Ob  = ws;            // [8192,1024]
  bf16_t* WT  = ws;            // [3072,1024] — aliases Ob, dead after QKV GEMM
  bf16_t* Qb  = ws + NB;       // [8192,1024]
  bf16_t* Kb  = Qb + NB;       // [8192,1024]
  bf16_t* VTb = Kb + NB;       // [64,64,2048]
  bf16_t* WpT = Qb;            // [1024,1024] — aliases Qb, written after flash
  bf16_t* xb  = (bf16_t*)d_out;// [8192,1024] — scratch in output buffer

  pack_w_kernel<<<dim3(16, 16, 3), 256, 0, stream>>>(Wq, Wk, Wv, WT);
  convert_bf16<<<dim3(4096), 256, 0, stream>>>(x, xb);
  gemm_qkv128<<<dim3(64, 24), 256, 0, stream>>>(xb, WT, Qb, Kb, VTb);
  flash_attn_kernel<<<dim3(512), 256, 0, stream>>>(Qb, Kb, VTb, Ob);
  convert_bf16<<<dim3(512), 256, 0, stream>>>(Wp, WpT);
  gemm_out128<<<dim3(64, 8), 256, 0, stream>>>(Ob, WpT, bp, out);
}

// Round 6
// 258.289 us; speedup vs baseline: 1.9075x; 1.0184x over previous
//
#include <hip/hip_runtime.h>
#include <hip/hip_bf16.h>
#include <math.h>

// B=4, S=2048, C=1024, H=16, HS=64
// Inputs (fp32, dict order): x[4,2048,1024], Wq/Wk/Wv[16,1024,64],
//                            Wp[1024,1024], bp[1024]
// Output: FP32 [4,2048,1024]
// R14: flash merged-pair blocks: 512 threads / 8 waves; waves 0-3 = long
//      q-tile (15-p), waves 4-7 = short q-tile (p), ONE shared KV stream
//      (short tile's KV range is a prefix of the long's). Staging iters
//      34 -> 32-2p (avg 25); 16 waves/CU (50% occupancy cap, was 25%).
//      p = ((g&3)<<1)|(g>>2) keeps co-resident blocks' durations adjacent;
//      id%8==bh%8 XCD pinning kept. Math unchanged.
//      GEMMs (R13 pipeline)/pack/convert unchanged.

typedef __bf16 bf16_t;
typedef __bf16 bf16x4_t __attribute__((ext_vector_type(4)));
typedef __bf16 bf16x8 __attribute__((ext_vector_type(8)));
typedef __bf16 bf16x2 __attribute__((ext_vector_type(2)));
typedef float f32x4 __attribute__((ext_vector_type(4)));
typedef float f32x16 __attribute__((ext_vector_type(16)));

#define S_LEN 2048
#define C_DIM 1024
#define NHEAD 16
#define HS_DIM 64
#define MROWS 8192   // B*S
#define QSCALE 0.18033688011112042f  // 0.125 * log2(e)

__device__ __forceinline__ void cvt8(bf16_t* dst, const float* __restrict__ src) {
  const float4 a = *(const float4*)src;
  const float4 b = *(const float4*)(src + 4);
  bf16x8 v;
  v[0] = (bf16_t)a.x; v[1] = (bf16_t)a.y; v[2] = (bf16_t)a.z; v[3] = (bf16_t)a.w;
  v[4] = (bf16_t)b.x; v[5] = (bf16_t)b.y; v[6] = (bf16_t)b.z; v[7] = (bf16_t)b.w;
  *(bf16x8*)dst = v;
}

// pack two f32 -> one u32 of 2xbf16 (compiler fuses to v_cvt_pk_bf16_f32; m240)
__device__ __forceinline__ unsigned int pk2(float a, float b) {
  union { bf16x2 h; unsigned int u; } t;
  t.h[0] = (bf16_t)a;
  t.h[1] = (bf16_t)b;
  return t.u;
}

// async global->LDS, 16B per lane; LDS dest = wave-uniform base + lane*16
__device__ __forceinline__ void gload16(const bf16_t* g, bf16_t* l) {
  __builtin_amdgcn_global_load_lds(
      (const __attribute__((address_space(1))) unsigned int*)(const void*)g,
      (__attribute__((address_space(3))) unsigned int*)(void*)l,
      16, 0, 0);
}

#define SBAR()  { __builtin_amdgcn_sched_barrier(0); \
                  __builtin_amdgcn_s_barrier();      \
                  __builtin_amdgcn_sched_barrier(0); }
#define VMCNT(N) { asm volatile("s_waitcnt vmcnt(" #N ")" ::: "memory"); \
                   __builtin_amdgcn_sched_barrier(0); }
#define LGKMCNT0() { asm volatile("s_waitcnt lgkmcnt(0)" ::: "memory"); \
                     __builtin_amdgcn_sched_barrier(0); }

// ---------------------------------------------------------------------------
// Elementwise fp32 -> bf16 convert (8 elems/thread). Used for x and Wp.
// ---------------------------------------------------------------------------
__global__ __launch_bounds__(256) void convert_bf16(
    const float* __restrict__ src, bf16_t* __restrict__ dst) {
  const size_t i = ((size_t)blockIdx.x * 256 + threadIdx.x) * 8;
  cvt8(dst + i, src + i);
}

// ---------------------------------------------------------------------------
// Pack Wq,Wk,Wv (fp32 [16,1024,64]) -> bf16 WT[3072,1024]:
// WT[wsel*1024+h*64+d][c] = W[h][c][d].
// ---------------------------------------------------------------------------
__global__ __launch_bounds__(256) void pack_w_kernel(
    const float* __restrict__ Wq, const float* __restrict__ Wk,
    const float* __restrict__ Wv, bf16_t* __restrict__ WT) {
  __shared__ __align__(16) float tile[64][68];
  const int wsel = blockIdx.z;
  const int h = blockIdx.y;
  const int c0 = blockIdx.x * 64;
  const float* W = (wsel == 0 ? Wq : (wsel == 1 ? Wk : Wv)) + (size_t)h * (C_DIM * HS_DIM);
  const int tr = threadIdx.x >> 2;          // 0..63 (c-row within tile)
  const int tc = (threadIdx.x & 3) << 4;    // 0,16,32,48
  #pragma unroll
  for (int j = 0; j < 16; j += 4)
    *(float4*)&tile[tr][tc + j] = *(const float4*)(W + (size_t)(c0 + tr) * HS_DIM + tc + j);
  __syncthreads();
  const int d = threadIdx.x >> 2;           // 0..63
  const int cb = (threadIdx.x & 3) << 4;    // 0,16,32,48
  bf16_t* dst = WT + ((size_t)(wsel * 1024 + h * 64 + d)) * C_DIM + c0 + cb;
  #pragma unroll
  for (int i = 0; i < 16; ++i) dst[i] = (bf16_t)tile[cb + i][d];
}

// ---------------------------------------------------------------------------
// QKV projection: xb[8192,1024](bf16) x WT[3072,1024](bf16)^T.
// R13 pipeline: frag-preload -> barrier -> early STAGE(kt+2) -> MFMA.
// 128x128x64 tiles, 4 waves 2x2, 4x4 accs/wave. Q pre-scaled by QSCALE.
// ---------------------------------------------------------------------------
__global__ __launch_bounds__(256, 2) void gemm_qkv128(
    const bf16_t* __restrict__ A, const bf16_t* __restrict__ WT,
    bf16_t* __restrict__ Q, bf16_t* __restrict__ K, bf16_t* __restrict__ VT) {
  __shared__ __align__(16) bf16_t As[2][128 * 64];
  __shared__ __align__(16) bf16_t Bs[2][128 * 64];
  const int m0 = blockIdx.x * 128;
  const int n0 = blockIdx.y * 128;
  const int tid = threadIdx.x;
  const int wave = tid >> 6, lane = tid & 63, quad = lane >> 4, lid = lane & 15;
  const int ww = wave >> 1, wc = wave & 1;
  const int lr = lane >> 3;                 // 0..7 (row within 8-row chunk)
  const int lc = (lane & 7) << 3;           // element col 0,8,...,56

  const bf16_t* Ag = A  + (size_t)m0 * C_DIM;
  const bf16_t* Bg = WT + (size_t)n0 * C_DIM;

  f32x4 acc[4][4] = {};

  #define STAGE_QKV(D, KT)                                                   \
    {                                                                        \
      const int k0_ = (KT) * 64;                                             \
      _Pragma("unroll")                                                      \
      for (int j = 0; j < 4; ++j) {                                          \
        const int row_ = wave * 32 + j * 8;                                  \
        gload16(Ag + (size_t)(row_ + lr) * C_DIM + k0_ + lc, &As[D][row_ * 64]); \
        gload16(Bg + (size_t)(row_ + lr) * C_DIM + k0_ + lc, &Bs[D][row_ * 64]); \
      }                                                                      \
    }

  STAGE_QKV(0, 0)
  STAGE_QKV(1, 1)

  #pragma unroll 1
  for (int kt = 0; kt < 16; ++kt) {
    const int d = kt & 1;
    if (kt < 15) { VMCNT(8) } else { VMCNT(0) }
    SBAR()                       // all waves' kt-tile loads landed

    // frag-preload: consume buf d entirely into VGPRs
    const bf16_t* Asd = As[d];
    const bf16_t* Bsd = Bs[d];
    bf16x8 af[2][4], bfr[2][4];
    #pragma unroll
    for (int c = 0; c < 2; ++c) {
      #pragma unroll
      for (int mt = 0; mt < 4; ++mt)
        af[c][mt] = *(const bf16x8*)&Asd[(ww * 64 + mt * 16 + lid) * 64 + c * 32 + quad * 8];
      #pragma unroll
      for (int nt = 0; nt < 4; ++nt)
        bfr[c][nt] = *(const bf16x8*)&Bsd[(wc * 64 + nt * 16 + lid) * 64 + c * 32 + quad * 8];
    }
    LGKMCNT0()                   // this wave's ds_reads retired (rule #18)
    SBAR()                       // all waves done reading buf d

    // early stage: issue kt+2 into the just-freed buffer BEFORE the MFMAs
    if (kt + 2 < 16) {
      if (d == 0) { STAGE_QKV(0, kt + 2) } else { STAGE_QKV(1, kt + 2) }
    }
    __builtin_amdgcn_sched_barrier(0);   // pin: loads issue before MFMA block

    #pragma unroll
    for (int c = 0; c < 2; ++c)
      #pragma unroll
      for (int mt = 0; mt < 4; ++mt)
        #pragma unroll
        for (int nt = 0; nt < 4; ++nt)
          acc[mt][nt] = __builtin_amdgcn_mfma_f32_16x16x32_bf16(af[c][mt], bfr[c][nt], acc[mt][nt], 0, 0, 0);
  }

  // wsel is block-uniform (each 128-col block lies inside one of Q/K/V)
  const int wsel = n0 >> 10;
  const float qs = (wsel == 0) ? QSCALE : 1.0f;
  #pragma unroll
  for (int mt = 0; mt < 4; ++mt) {
    #pragma unroll
    for (int nt = 0; nt < 4; ++nt) {
      const int row0 = m0 + ww * 64 + mt * 16 + quad * 4;
      const int col = n0 + wc * 64 + nt * 16 + lid;
      const int h = (col >> 6) & 15, dd = col & 63;
      if (wsel == 2) {
        bf16x4_t pv;
        #pragma unroll
        for (int r = 0; r < 4; ++r) pv[r] = (bf16_t)acc[mt][nt][r];
        const int b = row0 >> 11, s = row0 & 2047;
        *(bf16x4_t*)&VT[((size_t)(b * NHEAD + h) * HS_DIM + dd) * S_LEN + s] = pv;
      } else {
        bf16_t* dst = (wsel == 0 ? Q : K);
        #pragma unroll
        for (int r = 0; r < 4; ++r)
          dst[(size_t)(row0 + r) * C_DIM + h * HS_DIM + dd] = (bf16_t)(acc[mt][nt][r] * qs);
      }
    }
  }
}

// ---------------------------------------------------------------------------
// Flash attention (causal), swapped-QK^T 32x32 structure, MERGED-PAIR blocks.
// grid flat 512, 512 threads (8 waves). bh = id&63 (XCD pin), g = id>>6,
// p = ((g&3)<<1)|(g>>2). Waves 0-3 own q-tile (15-p)'s 128 rows; waves 4-7
// own q-tile p's 128 rows. ONE KV stream of nIter = 2*(15-p)+2 tiles serves
// both (short tile's range is a prefix); short waves skip compute past their
// diagonal via the existing wave-uniform branch.
// ---------------------------------------------------------------------------
#define PACK_GROUP(SV, BASE, FR)                                         \
  {                                                                      \
    unsigned int w0 = pk2(SV[BASE + 0], SV[BASE + 1]);                   \
    unsigned int w1 = pk2(SV[BASE + 2], SV[BASE + 3]);                   \
    unsigned int w2 = pk2(SV[BASE + 4], SV[BASE + 5]);                   \
    unsigned int w3 = pk2(SV[BASE + 6], SV[BASE + 7]);                   \
    auto sA = __builtin_amdgcn_permlane32_swap(w0, w2, false, false);    \
    auto sB = __builtin_amdgcn_permlane32_swap(w1, w3, false, false);    \
    FR.u[0] = sA[0]; FR.u[2] = sA[1];                                    \
    FR.u[1] = sB[0]; FR.u[3] = sB[1];                                    \
  }

union PFrag { bf16x8 v; unsigned int u[4]; };

__global__ __launch_bounds__(512, 4) void flash_attn_kernel(
    const bf16_t* __restrict__ Q,   // [8192,1024] (pre-scaled by QSCALE)
    const bf16_t* __restrict__ Kb,  // [8192,1024]
    const bf16_t* __restrict__ VT,  // [64,64,2048]
    bf16_t* __restrict__ O) {       // [8192,1024]
  __shared__ __align__(16) bf16_t Ks[2][64][64];
  __shared__ __align__(16) bf16_t Vs[2][64][64];
  const int id = blockIdx.x;
  const int bh = id & 63;                    // id%8 == bh%8 -> XCD locality
  const int g = id >> 6;                     // 0..7
  const int p = ((g & 3) << 1) | (g >> 2);   // co-resident blocks adjacent
  const int b = bh >> 4, h = bh & 15;
  const int rb = b * S_LEN;
  const int tid = threadIdx.x;
  const int wave = tid >> 6, lane = tid & 63;
  const int l31 = lane & 31, hi = lane >> 5;

  // wave -> q-tile: waves 0-3 = long tile (15-p), waves 4-7 = short tile (p)
  const int myTile = (wave < 4) ? (15 - p) : p;
  const int qw = myTile * 128 + (wave & 3) * 32;   // wave's first q row

  // staging coords: 512 thr x 16B = full 64-row x 128B tile per buffer
  const int srow = tid >> 3;                 // 0..63
  const int scol = (tid & 7) << 3;           // element col 0,8,...,56
  const int swcol = scol ^ ((srow & 7) << 3);// XOR-swizzled store col
  const int rsw = (lane & 7) << 3;           // read swizzle term

  const bf16_t* kbase = Kb + (size_t)(rb + srow) * C_DIM + h * HS_DIM + scol;
  const bf16_t* vbase = VT + ((size_t)bh * HS_DIM + srow) * S_LEN + scol;

  // Q fragments (B-operand): col q = l31, chunk c: d = c*16 + hi*8 + j
  bf16x8 qfrag[4];
  {
    const bf16_t* qp = Q + (size_t)(rb + qw + l31) * C_DIM + h * HS_DIM + hi * 8;
    #pragma unroll
    for (int c = 0; c < 4; ++c) qfrag[c] = *(const bf16x8*)(qp + c * 16);
  }

  f32x16 oacc0 = {}, oacc1 = {};   // d-tiles 0 (d=l31) and 1 (d=32+l31)
  float m_i = -INFINITY, l_i = 0.f;
  const int nIter = 2 * (15 - p) + 2;        // long tile's KV range

  // Prolog: stage tile 0 -> buffer 0 (one K + one V uint4 per thread)
  {
    uint4 k0 = *(const uint4*)(kbase);
    uint4 v0 = *(const uint4*)(vbase);
    *(uint4*)&Ks[0][srow][swcol] = k0;
    *(uint4*)&Vs[0][srow][swcol] = v0;
  }
  __syncthreads();

  for (int i = 0; i < nIter; ++i) {
    const int pb = i & 1;
    const int t0 = i << 6;

    // register prefetch of next tile (overlaps compute)
    uint4 k0r, v0r;
    const bool haveNext = (i + 1 < nIter);
    if (haveNext) {
      k0r = *(const uint4*)(kbase + (size_t)(t0 + 64) * C_DIM);
      v0r = *(const uint4*)(vbase + (t0 + 64));
    }

    if (t0 < qw + 32) {   // wave-uniform causal skip
      // ---- QK^T (swapped): sacc[t][q], t-tiles 0/1 ----
      f32x16 sa0 = {}, sa1 = {};
      __builtin_amdgcn_s_setprio(1);
      #pragma unroll
      for (int c = 0; c < 4; ++c) {
        const int col = (c * 16 + hi * 8) ^ rsw;
        bf16x8 kf0 = *(const bf16x8*)&Ks[pb][l31][col];
        bf16x8 kf1 = *(const bf16x8*)&Ks[pb][l31 + 32][col];
        sa0 = __builtin_amdgcn_mfma_f32_32x32x16_bf16(kf0, qfrag[c], sa0, 0, 0, 0);
        sa1 = __builtin_amdgcn_mfma_f32_32x32x16_bf16(kf1, qfrag[c], sa1, 0, 0, 0);
      }
      __builtin_amdgcn_s_setprio(0);

      // causal mask (diag tiles only; scores pre-scaled via Q)
      const bool diag = (t0 + 63 > qw);
      if (diag) {
        const int qg = qw + l31;
        #pragma unroll
        for (int r = 0; r < 16; ++r) {
          const int tr = (r & 3) + 8 * (r >> 2) + 4 * hi;
          if (t0 + tr > qg)      sa0[r] = -INFINITY;
          if (t0 + 32 + tr > qg) sa1[r] = -INFINITY;
        }
      }

      // in-register row max + cross-half combine
      float pmax = -INFINITY;
      #pragma unroll
      for (int r = 0; r < 16; ++r) pmax = fmaxf(pmax, fmaxf(sa0[r], sa1[r]));
      pmax = fmaxf(pmax, __shfl_xor(pmax, 32));

      // defer-max rescale (T13): only rescale when max grew by > 8 (exp2 dom)
      if (!__all(pmax <= m_i + 8.f)) {
        const float mnew = fmaxf(m_i, pmax);
        const float alpha = exp2f(m_i - mnew);
        m_i = mnew;
        l_i *= alpha;
        #pragma unroll
        for (int r = 0; r < 16; ++r) {
          const float av = __shfl(alpha, (r & 3) + 8 * (r >> 2) + 4 * hi);
          oacc0[r] *= av;
          oacc1[r] *= av;
        }
      }

      // P = exp2(s - m), row sum
      float rsum = 0.f;
      #pragma unroll
      for (int r = 0; r < 16; ++r) {
        const float p0 = exp2f(sa0[r] - m_i);
        const float p1 = exp2f(sa1[r] - m_i);
        sa0[r] = p0; sa1[r] = p1;
        rsum += p0 + p1;
      }
      rsum += __shfl_xor(rsum, 32);
      l_i += rsum;

      // pack P -> 4 A-frags (ks = t/16) via cvt-pk + permlane32_swap (T12)
      PFrag pf[4];
      PACK_GROUP(sa0, 0, pf[0])
      PACK_GROUP(sa0, 8, pf[1])
      PACK_GROUP(sa1, 0, pf[2])
      PACK_GROUP(sa1, 8, pf[3])

      // ---- PV ----
      __builtin_amdgcn_s_setprio(1);
      #pragma unroll
      for (int ks = 0; ks < 4; ++ks) {
        const int col = (ks * 16 + hi * 8) ^ rsw;
        bf16x8 vf0 = *(const bf16x8*)&Vs[pb][l31][col];
        bf16x8 vf1 = *(const bf16x8*)&Vs[pb][l31 + 32][col];
        oacc0 = __builtin_amdgcn_mfma_f32_32x32x16_bf16(pf[ks].v, vf0, oacc0, 0, 0, 0);
        oacc1 = __builtin_amdgcn_mfma_f32_32x32x16_bf16(pf[ks].v, vf1, oacc1, 0, 0, 0);
      }
      __builtin_amdgcn_s_setprio(0);
    }

    // write prefetched tile into the idle buffer; single barrier/iter
    if (haveNext) {
      *(uint4*)&Ks[1 - pb][srow][swcol] = k0r;
      *(uint4*)&Vs[1 - pb][srow][swcol] = v0r;
      __syncthreads();
    }
  }

  // epilogue: O = oacc / l  (broadcast 1/l from lane q to row layout)
  const float linv = 1.f / l_i;
  #pragma unroll
  for (int r = 0; r < 16; ++r) {
    const int qrow = (r & 3) + 8 * (r >> 2) + 4 * hi;
    const float inv = __shfl(linv, qrow);
    const int row = rb + qw + qrow;
    O[(size_t)row * C_DIM + h * HS_DIM + l31]      = (bf16_t)(oacc0[r] * inv);
    O[(size_t)row * C_DIM + h * HS_DIM + 32 + l31] = (bf16_t)(oacc1[r] * inv);
  }
}

// ---------------------------------------------------------------------------
// Output projection: out = O @ WpT^T + bp (fp32 stores). R13 pipeline.
// ---------------------------------------------------------------------------
__global__ __launch_bounds__(256, 2) void gemm_out128(
    const bf16_t* __restrict__ A,    // [8192,1024] O (bf16)
    const bf16_t* __restrict__ Bw,   // [1024,1024] Wp (bf16)
    const float* __restrict__ bias,  // [1024]
    float* __restrict__ out) {       // [8192,1024] fp32
  __shared__ __align__(16) bf16_t As[2][128 * 64];
  __shared__ __align__(16) bf16_t Bs[2][128 * 64];
  const int m0 = blockIdx.x * 128;
  const int n0 = blockIdx.y * 128;
  const int tid = threadIdx.x;
  const int wave = tid >> 6, lane = tid & 63, quad = lane >> 4, lid = lane & 15;
  const int ww = wave >> 1, wc = wave & 1;
  const int lr = lane >> 3;
  const int lc = (lane & 7) << 3;

  const bf16_t* Ag = A  + (size_t)m0 * C_DIM;
  const bf16_t* Bg = Bw + (size_t)n0 * C_DIM;

  f32x4 acc[4][4] = {};

  #define STAGE_OUT(D, KT)                                                   \
    {                                                                        \
      const int k0_ = (KT) * 64;                                             \
      _Pragma("unroll")                                                      \
      for (int j = 0; j < 4; ++j) {                                          \
        const int row_ = wave * 32 + j * 8;                                  \
        gload16(Ag + (size_t)(row_ + lr) * C_DIM + k0_ + lc, &As[D][row_ * 64]); \
        gload16(Bg + (size_t)(row_ + lr) * C_DIM + k0_ + lc, &Bs[D][row_ * 64]); \
      }                                                                      \
    }

  STAGE_OUT(0, 0)
  STAGE_OUT(1, 1)

  #pragma unroll 1
  for (int kt = 0; kt < 16; ++kt) {
    const int d = kt & 1;
    if (kt < 15) { VMCNT(8) } else { VMCNT(0) }
    SBAR()

    const bf16_t* Asd = As[d];
    const bf16_t* Bsd = Bs[d];
    bf16x8 af[2][4], bfr[2][4];
    #pragma unroll
    for (int c = 0; c < 2; ++c) {
      #pragma unroll
      for (int mt = 0; mt < 4; ++mt)
        af[c][mt] = *(const bf16x8*)&Asd[(ww * 64 + mt * 16 + lid) * 64 + c * 32 + quad * 8];
      #pragma unroll
      for (int nt = 0; nt < 4; ++nt)
        bfr[c][nt] = *(const bf16x8*)&Bsd[(wc * 64 + nt * 16 + lid) * 64 + c * 32 + quad * 8];
    }
    LGKMCNT0()
    SBAR()

    if (kt + 2 < 16) {
      if (d == 0) { STAGE_OUT(0, kt + 2) } else { STAGE_OUT(1, kt + 2) }
    }
    __builtin_amdgcn_sched_barrier(0);

    #pragma unroll
    for (int c = 0; c < 2; ++c)
      #pragma unroll
      for (int mt = 0; mt < 4; ++mt)
        #pragma unroll
        for (int nt = 0; nt < 4; ++nt)
          acc[mt][nt] = __builtin_amdgcn_mfma_f32_16x16x32_bf16(af[c][mt], bfr[c][nt], acc[mt][nt], 0, 0, 0);
  }

  #pragma unroll
  for (int mt = 0; mt < 4; ++mt) {
    #pragma unroll
    for (int nt = 0; nt < 4; ++nt) {
      #pragma unroll
      for (int r = 0; r < 4; ++r) {
        const int row = m0 + ww * 64 + mt * 16 + quad * 4 + r;
        const int col = n0 + wc * 64 + nt * 16 + lid;
        out[(size_t)row * C_DIM + col] = acc[mt][nt][r] + bias[col];
      }
    }
  }
}

// ---------------------------------------------------------------------------
extern "C" void kernel_launch(void* const* d_in, const int* in_sizes, int n_in,
                              void* d_out, int out_size, void* d_ws, size_t ws_size,
                              hipStream_t stream) {
  const float *x, *Wq, *Wk, *Wv, *Wp, *bp;
  if (in_sizes[0] == MROWS * C_DIM) {            // dict order (confirmed)
    x  = (const float*)d_in[0];
    Wq = (const float*)d_in[1];
    Wk = (const float*)d_in[2];
    Wv = (const float*)d_in[3];
    Wp = (const float*)d_in[4];
    bp = (const float*)d_in[5];
  } else {                                        // key-sorted hedge
    Wk = (const float*)d_in[0];
    Wp = (const float*)d_in[1];
    Wq = (const float*)d_in[2];
    Wv = (const float*)d_in[3];
    bp = (const float*)d_in[4];
    x  = (const float*)d_in[5];
  }
  float* out = (float*)d_out;

  // ws = 64 MB: [Ob 16MB (WT aliases its first 6MB; dead before flash;
  //              WpT aliases Qb after flash)] [Qb 16MB][Kb 16MB][VTb 16MB]
  // xb (bf16 x) lives in the first 16MB of d_out (dead before gemm_out writes).
  const size_t NB = (size_t)MROWS * C_DIM;   // 8 M elements
  bf16_t* ws  = (bf16_t*)d_ws;
  bf16_t* Ob  = ws;            // [8192,1024]
  bf16_t* WT  = ws;            // [3072,1024] — aliases Ob, dead after QKV GEMM
  bf16_t* Qb  = ws + NB;       // [8192,1024]
  bf16_t* Kb  = Qb + NB;       // [8192,1024]
  bf16_t* VTb = Kb + NB;       // [64,64,2048]
  bf16_t* WpT = Qb;            // [1024,1024] — aliases Qb, written after flash
  bf16_t* xb  = (bf16_t*)d_out;// [8192,1024] — scratch in output buffer

  pack_w_kernel<<<dim3(16, 16, 3), 256, 0, stream>>>(Wq, Wk, Wv, WT);
  convert_bf16<<<dim3(4096), 256, 0, stream>>>(x, xb);
  gemm_qkv128<<<dim3(64, 24), 256, 0, stream>>>(xb, WT, Qb, Kb, VTb);
  flash_attn_kernel<<<dim3(512), 512, 0, stream>>>(Qb, Kb, VTb, Ob);
  convert_bf16<<<dim3(512), 256, 0, stream>>>(Wp, WpT);
  gemm_out128<<<dim3(64, 8), 256, 0, stream>>>(Ob, WpT, bp, out);
}